// Round 1
// baseline (3043.772 us; speedup 1.0000x reference)
//
#include <hip/hip_runtime.h>

// ---------------------------------------------------------------------------
// GCN encoder: mu, log = GCNConv(relu(GCNConv(x,W1,b1)), W_mu/W_log)
// Key identity: segment_sum((h@W)[src]*norm) == segment_sum(h[src]*norm) @ W
// so both output heads share ONE aggregation.
// ---------------------------------------------------------------------------

__global__ void k_deg(const int* __restrict__ dst, int E, int* __restrict__ deg) {
    int e = blockIdx.x * blockDim.x + threadIdx.x;
    if (e < E) atomicAdd(&deg[dst[e]], 1);
}

__global__ void k_dinv(const int* __restrict__ deg, float* __restrict__ dinv, int N) {
    int i = blockIdx.x * blockDim.x + threadIdx.x;
    if (i < N) dinv[i] = rsqrtf((float)(deg[i] + 1));   // +1 = self loop
}

// A[N,64] = x[N,128] @ W[128,64].  W staged in LDS (32KB), 4 rows/block.
__global__ __launch_bounds__(256) void k_gemm1(const float* __restrict__ x,
                                               const float* __restrict__ W,
                                               float* __restrict__ A, int N) {
    __shared__ float Ws[128 * 64];
    __shared__ float xs[4 * 128];
    for (int i = threadIdx.x; i < 128 * 64; i += 256) Ws[i] = W[i];
    int base = blockIdx.x << 2;
    int t = threadIdx.x;
    if (t < 128) {
        int row = base + (t >> 5);               // 32 float4 per 128-f32 row
        if (row < N) {
            float4 v = reinterpret_cast<const float4*>(x)[(size_t)row * 32 + (t & 31)];
            reinterpret_cast<float4*>(xs)[t] = v;
        }
    }
    __syncthreads();
    int ty = t >> 6, col = t & 63;
    float acc = 0.f;
    const float* xr = xs + ty * 128;
#pragma unroll
    for (int k = 0; k < 128; ++k) acc = fmaf(xr[k], Ws[k * 64 + col], acc);
    int row = base + ty;
    if (row < N) A[(size_t)row * 64 + col] = acc;
}

// out[dst,:] += feat[src,:] * dinv[src]*dinv[dst]  — 16 lanes per edge, float4.
__global__ __launch_bounds__(256) void k_agg(const int* __restrict__ ei, int E,
                                             const float* __restrict__ dinv,
                                             const float* __restrict__ feat,
                                             float* __restrict__ out) {
    int idx = blockIdx.x * 256 + threadIdx.x;
    int e = idx >> 4;
    if (e >= E) return;
    int f4 = (idx & 15) << 2;
    int s = ei[e];
    int d = ei[E + e];
    float norm = dinv[s] * dinv[d];
    float4 v = *reinterpret_cast<const float4*>(feat + (size_t)s * 64 + f4);
    float* o = out + (size_t)d * 64 + f4;
    atomicAdd(o + 0, v.x * norm);
    atomicAdd(o + 1, v.y * norm);
    atomicAdd(o + 2, v.z * norm);
    atomicAdd(o + 3, v.w * norm);
}

// B = relu(B + A*dinv^2 + b1)   (adds self-loop term + bias, in place)
__global__ void k_selfrelu(const float* __restrict__ A, float* __restrict__ B,
                           const float* __restrict__ dinv,
                           const float* __restrict__ b1, int N) {
    int idx = blockIdx.x * blockDim.x + threadIdx.x;
    if (idx >= N * 64) return;
    int i = idx >> 6, f = idx & 63;
    float di = dinv[i];
    float v = B[idx] + A[idx] * di * di + b1[f];
    B[idx] = v > 0.f ? v : 0.f;
}

// r = A + B*dinv^2 (self loop);  mu = r@Wmu+bmu;  log = r@Wlog+blog.
// 8 rows/block, 32 cols/row; both W in LDS.
__global__ __launch_bounds__(256) void k_final(const float* __restrict__ A,
                                               const float* __restrict__ B,
                                               const float* __restrict__ dinv,
                                               const float* __restrict__ Wmu,
                                               const float* __restrict__ bmu,
                                               const float* __restrict__ Wlg,
                                               const float* __restrict__ blg,
                                               float* __restrict__ out, int N) {
    __shared__ float Wm[64 * 32];
    __shared__ float Wl[64 * 32];
    __shared__ float r[8 * 64];
    for (int i = threadIdx.x; i < 64 * 32; i += 256) {
        Wm[i] = Wmu[i];
        Wl[i] = Wlg[i];
    }
    int base = blockIdx.x << 3;
    int t = threadIdx.x;
    if (t < 128) {
        int row = base + (t >> 4);               // 16 float4 per 64-f32 row
        if (row < N) {
            float4 a = reinterpret_cast<const float4*>(A)[(size_t)row * 16 + (t & 15)];
            float4 b = reinterpret_cast<const float4*>(B)[(size_t)row * 16 + (t & 15)];
            float di = dinv[row];
            float d2 = di * di;
            float4 v;
            v.x = a.x + b.x * d2;
            v.y = a.y + b.y * d2;
            v.z = a.z + b.z * d2;
            v.w = a.w + b.w * d2;
            reinterpret_cast<float4*>(r)[t] = v;
        }
    }
    __syncthreads();
    int ry = t >> 5, c = t & 31;
    float accm = bmu[c], accl = blg[c];
    const float* rr = r + ry * 64;
#pragma unroll
    for (int k = 0; k < 64; ++k) {
        float rv = rr[k];
        accm = fmaf(rv, Wm[k * 32 + c], accm);
        accl = fmaf(rv, Wl[k * 32 + c], accl);
    }
    int row = base + ry;
    if (row < N) {
        out[(size_t)row * 32 + c] = accm;
        out[(size_t)N * 32 + (size_t)row * 32 + c] = accl;
    }
}

extern "C" void kernel_launch(void* const* d_in, const int* in_sizes, int n_in,
                              void* d_out, int out_size, void* d_ws, size_t ws_size,
                              hipStream_t stream) {
    const float* x   = (const float*)d_in[0];
    const int*   ei  = (const int*)d_in[1];   // [2,E] flat: src then dst
    const float* W1  = (const float*)d_in[2];
    const float* b1  = (const float*)d_in[3];
    const float* Wmu = (const float*)d_in[4];
    const float* bmu = (const float*)d_in[5];
    const float* Wlg = (const float*)d_in[6];
    const float* blg = (const float*)d_in[7];
    float* out = (float*)d_out;

    const int N = in_sizes[0] / 128;
    const int E = in_sizes[1] / 2;

    // workspace layout: A[N*64] f32, B[N*64] f32, deg[N] i32, dinv[N] f32
    float* A    = (float*)d_ws;
    float* B    = A + (size_t)N * 64;
    int*   deg  = (int*)(B + (size_t)N * 64);
    float* dinv = (float*)(deg + N);

    hipMemsetAsync(deg, 0, (size_t)N * sizeof(int), stream);
    k_deg<<<(E + 255) / 256, 256, 0, stream>>>(ei + E, E, deg);
    k_dinv<<<(N + 255) / 256, 256, 0, stream>>>(deg, dinv, N);

    k_gemm1<<<(N + 3) / 4, 256, 0, stream>>>(x, W1, A, N);

    hipMemsetAsync(B, 0, (size_t)N * 64 * sizeof(float), stream);
    k_agg<<<(int)(((size_t)E * 16 + 255) / 256), 256, 0, stream>>>(ei, E, dinv, A, B);
    k_selfrelu<<<(int)(((size_t)N * 64 + 255) / 256), 256, 0, stream>>>(A, B, dinv, b1, N);

    hipMemsetAsync(A, 0, (size_t)N * 64 * sizeof(float), stream);
    k_agg<<<(int)(((size_t)E * 16 + 255) / 256), 256, 0, stream>>>(ei, E, dinv, B, A);

    k_final<<<(N + 7) / 8, 256, 0, stream>>>(A, B, dinv, Wmu, bmu, Wlg, blg, out, N);
}

// Round 2
// 552.128 us; speedup vs baseline: 5.5128x; 5.5128x over previous
//
#include <hip/hip_runtime.h>

// ---------------------------------------------------------------------------
// GCN encoder: mu, log = GCNConv(relu(GCNConv(x,W1,b1)), W_mu/W_log)
// Identity: segment_sum((h@W)[src]*norm) == segment_sum(h[src]*norm) @ W
// -> both output heads share ONE aggregation.
// R1: replace f32-atomic scatter (write-through, 1.6GB HBM writes/pass) with
// CSR build (deg -> scan -> cursor scatter) + gather-accumulate aggregation.
// Epilogues (self-loop, bias, relu, r-combine) fused into the agg kernels.
// ---------------------------------------------------------------------------

__global__ void k_deg(const int* __restrict__ dst, int E, int* __restrict__ deg) {
    int e = blockIdx.x * blockDim.x + threadIdx.x;
    if (e < E) atomicAdd(&deg[dst[e]], 1);
}

__global__ void k_dinv(const int* __restrict__ deg, float* __restrict__ dinv, int N) {
    int i = blockIdx.x * blockDim.x + threadIdx.x;
    if (i < N) dinv[i] = rsqrtf((float)(deg[i] + 1));   // +1 = self loop
}

// ---- two-level exclusive scan of deg[N] -> rowptr[N+1] ----------------------
// scan1: 1024 elems/block (256 thr x int4), block-exclusive results + partial
__global__ __launch_bounds__(256) void k_scan1(const int* __restrict__ deg,
                                               int* __restrict__ rowptr,
                                               int* __restrict__ partial, int N) {
    __shared__ int sdata[256];
    int t = threadIdx.x;
    int idx = blockIdx.x * 1024 + t * 4;
    int4 v = {0, 0, 0, 0};
    if (idx + 3 < N) {
        v = *reinterpret_cast<const int4*>(deg + idx);
    } else {
        int* p = (int*)&v;
        for (int k = 0; k < 4; ++k) p[k] = (idx + k < N) ? deg[idx + k] : 0;
    }
    int s0 = v.x, s1 = s0 + v.y, s2 = s1 + v.z, s3 = s2 + v.w;
    sdata[t] = s3;
    __syncthreads();
    for (int off = 1; off < 256; off <<= 1) {
        int val = (t >= off) ? sdata[t - off] : 0;
        __syncthreads();
        sdata[t] += val;
        __syncthreads();
    }
    int excl = (t > 0) ? sdata[t - 1] : 0;
    if (t == 255) partial[blockIdx.x] = sdata[255];
    int4 o;
    o.x = excl; o.y = excl + s0; o.z = excl + s1; o.w = excl + s2;
    if (idx + 3 < N) {
        *reinterpret_cast<int4*>(rowptr + idx) = o;
    } else {
        int* p = (int*)&o;
        for (int k = 0; k < 4; ++k) if (idx + k < N) rowptr[idx + k] = p[k];
    }
}

// scan2: single block scans the partials in place (exclusive); sets rowptr[N]=E
__global__ __launch_bounds__(256) void k_scan2(int* __restrict__ partial, int NP,
                                               int* __restrict__ rowptr, int N, int E) {
    __shared__ int sdata[256];
    int t = threadIdx.x;
    int val = (t < NP) ? partial[t] : 0;
    sdata[t] = val;
    __syncthreads();
    for (int off = 1; off < 256; off <<= 1) {
        int v2 = (t >= off) ? sdata[t - off] : 0;
        __syncthreads();
        sdata[t] += v2;
        __syncthreads();
    }
    if (t < NP) partial[t] = sdata[t] - val;   // exclusive
    if (t == 0) rowptr[N] = E;
}

// scan3: add block offsets
__global__ void k_scan3(int* __restrict__ rowptr, const int* __restrict__ partial, int N) {
    int i = blockIdx.x * blockDim.x + threadIdx.x;
    if (i < N) rowptr[i] += partial[i >> 10];
}

// cursor-scatter src indices into CSR order
__global__ void k_scatter(const int* __restrict__ ei, int E,
                          const int* __restrict__ rowptr,
                          int* __restrict__ cursor, int* __restrict__ ssrc) {
    int e = blockIdx.x * blockDim.x + threadIdx.x;
    if (e >= E) return;
    int s = ei[e];
    int d = ei[E + e];
    int pos = atomicAdd(&cursor[d], 1);
    ssrc[rowptr[d] + pos] = s;
}

// A[N,64] = x[N,128] @ W[128,64].  W staged in LDS (32KB), 4 rows/block.
__global__ __launch_bounds__(256) void k_gemm1(const float* __restrict__ x,
                                               const float* __restrict__ W,
                                               float* __restrict__ A, int N) {
    __shared__ float Ws[128 * 64];
    __shared__ float xs[4 * 128];
    for (int i = threadIdx.x; i < 128 * 64; i += 256) Ws[i] = W[i];
    int base = blockIdx.x << 2;
    int t = threadIdx.x;
    if (t < 128) {
        int row = base + (t >> 5);
        if (row < N) {
            float4 v = reinterpret_cast<const float4*>(x)[(size_t)row * 32 + (t & 31)];
            reinterpret_cast<float4*>(xs)[t] = v;
        }
    }
    __syncthreads();
    int ty = t >> 6, col = t & 63;
    float acc = 0.f;
    const float* xr = xs + ty * 128;
#pragma unroll
    for (int k = 0; k < 128; ++k) acc = fmaf(xr[k], Ws[k * 64 + col], acc);
    int row = base + ty;
    if (row < N) A[(size_t)row * 64 + col] = acc;
}

// CSR gather-aggregate: out[d] = f( sum_{s in adj(d)} feat[s]*dinv[s] * dinv[d] , other[d] )
// EPI==1: out = relu(agg + other*dinv^2 + bias)   (layer-1 epilogue)
// EPI==2: out = agg + other*dinv^2                (r for the final dual GEMV)
template <int EPI>
__global__ __launch_bounds__(256) void k_aggcsr(const int* __restrict__ rowptr,
                                                const int* __restrict__ ssrc,
                                                const float* __restrict__ dinv,
                                                const float* __restrict__ feat,
                                                const float* __restrict__ other,
                                                const float* __restrict__ bias,
                                                float* __restrict__ out, int N) {
    int idx = blockIdx.x * 256 + threadIdx.x;
    int g = idx >> 4;
    if (g >= N) return;
    int f4 = (idx & 15) << 2;
    int beg = rowptr[g], end = rowptr[g + 1];
    float4 acc = {0.f, 0.f, 0.f, 0.f};
    for (int j = beg; j < end; ++j) {
        int s = ssrc[j];
        float ns = dinv[s];
        float4 v = *reinterpret_cast<const float4*>(feat + (size_t)s * 64 + f4);
        acc.x = fmaf(v.x, ns, acc.x);
        acc.y = fmaf(v.y, ns, acc.y);
        acc.z = fmaf(v.z, ns, acc.z);
        acc.w = fmaf(v.w, ns, acc.w);
    }
    float dd = dinv[g];
    float d2 = dd * dd;
    float4 o = *reinterpret_cast<const float4*>(other + (size_t)g * 64 + f4);
    float4 r;
    if (EPI == 1) {
        float4 bv = *reinterpret_cast<const float4*>(bias + f4);
        r.x = fmaf(acc.x, dd, fmaf(o.x, d2, bv.x));
        r.y = fmaf(acc.y, dd, fmaf(o.y, d2, bv.y));
        r.z = fmaf(acc.z, dd, fmaf(o.z, d2, bv.z));
        r.w = fmaf(acc.w, dd, fmaf(o.w, d2, bv.w));
        r.x = r.x > 0.f ? r.x : 0.f;
        r.y = r.y > 0.f ? r.y : 0.f;
        r.z = r.z > 0.f ? r.z : 0.f;
        r.w = r.w > 0.f ? r.w : 0.f;
    } else {
        r.x = fmaf(acc.x, dd, o.x * d2);
        r.y = fmaf(acc.y, dd, o.y * d2);
        r.z = fmaf(acc.z, dd, o.z * d2);
        r.w = fmaf(acc.w, dd, o.w * d2);
    }
    *reinterpret_cast<float4*>(out + (size_t)g * 64 + f4) = r;
}

// mu = r@Wmu+bmu; log = r@Wlog+blog.  8 rows/block, 32 cols/row; W in LDS.
__global__ __launch_bounds__(256) void k_final(const float* __restrict__ R,
                                               const float* __restrict__ Wmu,
                                               const float* __restrict__ bmu,
                                               const float* __restrict__ Wlg,
                                               const float* __restrict__ blg,
                                               float* __restrict__ out, int N) {
    __shared__ float Wm[64 * 32];
    __shared__ float Wl[64 * 32];
    __shared__ float r[8 * 64];
    for (int i = threadIdx.x; i < 64 * 32; i += 256) {
        Wm[i] = Wmu[i];
        Wl[i] = Wlg[i];
    }
    int base = blockIdx.x << 3;
    int t = threadIdx.x;
    if (t < 128) {
        int row = base + (t >> 4);
        if (row < N) {
            float4 v = reinterpret_cast<const float4*>(R)[(size_t)row * 16 + (t & 15)];
            reinterpret_cast<float4*>(r)[t] = v;
        }
    }
    __syncthreads();
    int ry = t >> 5, c = t & 31;
    float accm = bmu[c], accl = blg[c];
    const float* rr = r + ry * 64;
#pragma unroll
    for (int k = 0; k < 64; ++k) {
        float rv = rr[k];
        accm = fmaf(rv, Wm[k * 32 + c], accm);
        accl = fmaf(rv, Wl[k * 32 + c], accl);
    }
    int row = base + ry;
    if (row < N) {
        out[(size_t)row * 32 + c] = accm;
        out[(size_t)N * 32 + (size_t)row * 32 + c] = accl;
    }
}

extern "C" void kernel_launch(void* const* d_in, const int* in_sizes, int n_in,
                              void* d_out, int out_size, void* d_ws, size_t ws_size,
                              hipStream_t stream) {
    const float* x   = (const float*)d_in[0];
    const int*   ei  = (const int*)d_in[1];   // [2,E] flat: src then dst
    const float* W1  = (const float*)d_in[2];
    const float* b1  = (const float*)d_in[3];
    const float* Wmu = (const float*)d_in[4];
    const float* bmu = (const float*)d_in[5];
    const float* Wlg = (const float*)d_in[6];
    const float* blg = (const float*)d_in[7];
    float* out = (float*)d_out;

    const int N = in_sizes[0] / 128;
    const int E = in_sizes[1] / 2;

    // workspace layout (all 16B-aligned where vector-accessed):
    // A[N*64] f32 | B[N*64] f32 | ssrc[E] i32 | deg[N] i32 | rowptr[N+1] i32
    // | cursor[N] i32 | dinv[N] f32 | partial[256] i32
    float* A      = (float*)d_ws;
    float* B      = A + (size_t)N * 64;
    int*   ssrc   = (int*)(B + (size_t)N * 64);
    int*   deg    = ssrc + E;
    int*   rowptr = deg + N;
    int*   cursor = rowptr + (N + 1);
    float* dinv   = (float*)(cursor + N);
    int*   partial = (int*)(dinv + N);

    const int NP = (N + 1023) / 1024;   // number of scan partials (<=256)

    hipMemsetAsync(deg, 0, (size_t)N * sizeof(int), stream);
    hipMemsetAsync(cursor, 0, (size_t)N * sizeof(int), stream);

    k_deg<<<(E + 255) / 256, 256, 0, stream>>>(ei + E, E, deg);
    k_dinv<<<(N + 255) / 256, 256, 0, stream>>>(deg, dinv, N);

    k_scan1<<<NP, 256, 0, stream>>>(deg, rowptr, partial, N);
    k_scan2<<<1, 256, 0, stream>>>(partial, NP, rowptr, N, E);
    k_scan3<<<(N + 255) / 256, 256, 0, stream>>>(rowptr, partial, N);
    k_scatter<<<(E + 255) / 256, 256, 0, stream>>>(ei, E, rowptr, cursor, ssrc);

    k_gemm1<<<(N + 3) / 4, 256, 0, stream>>>(x, W1, A, N);

    // layer 1: B = relu(agg(A) + A*dinv^2 + b1)
    k_aggcsr<1><<<(int)(((size_t)N * 16 + 255) / 256), 256, 0, stream>>>(
        rowptr, ssrc, dinv, A, A, b1, B, N);
    // layer 2 shared aggregation: A = agg(B) + B*dinv^2   (this is r)
    k_aggcsr<2><<<(int)(((size_t)N * 16 + 255) / 256), 256, 0, stream>>>(
        rowptr, ssrc, dinv, B, B, b1, A, N);

    k_final<<<(N + 7) / 8, 256, 0, stream>>>(A, Wmu, bmu, Wlg, blg, out, N);
}

// Round 3
// 465.558 us; speedup vs baseline: 6.5379x; 1.1859x over previous
//
#include <hip/hip_runtime.h>

// ---------------------------------------------------------------------------
// GCN encoder: mu, log = GCNConv(relu(GCNConv(x,W1,b1)), W_mu/W_log)
// Identity: segment_sum((h@W)[src]*norm) == segment_sum(h[src]*norm) @ W
// -> both output heads share ONE aggregation.
// R1: CSR build + gather-aggregate (killed f32-atomic write-through).
// R2: single atomic pass — k_degpos returns each edge's rank via the
//     histogram atomicAdd; scatter becomes atomic-free (cursor deleted,
//     pos[E] aliases B). Kills k_scatter's 107MB atomic write-through.
// ---------------------------------------------------------------------------

// deg histogram + per-edge rank in one atomic pass
__global__ void k_degpos(const int* __restrict__ dst, int E,
                         int* __restrict__ deg, int* __restrict__ pos) {
    int e = blockIdx.x * blockDim.x + threadIdx.x;
    if (e < E) pos[e] = atomicAdd(&deg[dst[e]], 1);
}

__global__ void k_dinv(const int* __restrict__ deg, float* __restrict__ dinv, int N) {
    int i = blockIdx.x * blockDim.x + threadIdx.x;
    if (i < N) dinv[i] = rsqrtf((float)(deg[i] + 1));   // +1 = self loop
}

// ---- two-level exclusive scan of deg[N] -> rowptr[N+1] ----------------------
__global__ __launch_bounds__(256) void k_scan1(const int* __restrict__ deg,
                                               int* __restrict__ rowptr,
                                               int* __restrict__ partial, int N) {
    __shared__ int sdata[256];
    int t = threadIdx.x;
    int idx = blockIdx.x * 1024 + t * 4;
    int4 v = {0, 0, 0, 0};
    if (idx + 3 < N) {
        v = *reinterpret_cast<const int4*>(deg + idx);
    } else {
        int* p = (int*)&v;
        for (int k = 0; k < 4; ++k) p[k] = (idx + k < N) ? deg[idx + k] : 0;
    }
    int s0 = v.x, s1 = s0 + v.y, s2 = s1 + v.z, s3 = s2 + v.w;
    sdata[t] = s3;
    __syncthreads();
    for (int off = 1; off < 256; off <<= 1) {
        int val = (t >= off) ? sdata[t - off] : 0;
        __syncthreads();
        sdata[t] += val;
        __syncthreads();
    }
    int excl = (t > 0) ? sdata[t - 1] : 0;
    if (t == 255) partial[blockIdx.x] = sdata[255];
    int4 o;
    o.x = excl; o.y = excl + s0; o.z = excl + s1; o.w = excl + s2;
    if (idx + 3 < N) {
        *reinterpret_cast<int4*>(rowptr + idx) = o;
    } else {
        int* p = (int*)&o;
        for (int k = 0; k < 4; ++k) if (idx + k < N) rowptr[idx + k] = p[k];
    }
}

__global__ __launch_bounds__(256) void k_scan2(int* __restrict__ partial, int NP,
                                               int* __restrict__ rowptr, int N, int E) {
    __shared__ int sdata[256];
    int t = threadIdx.x;
    int val = (t < NP) ? partial[t] : 0;
    sdata[t] = val;
    __syncthreads();
    for (int off = 1; off < 256; off <<= 1) {
        int v2 = (t >= off) ? sdata[t - off] : 0;
        __syncthreads();
        sdata[t] += v2;
        __syncthreads();
    }
    if (t < NP) partial[t] = sdata[t] - val;   // exclusive
    if (t == 0) rowptr[N] = E;
}

__global__ void k_scan3(int* __restrict__ rowptr, const int* __restrict__ partial, int N) {
    int i = blockIdx.x * blockDim.x + threadIdx.x;
    if (i < N) rowptr[i] += partial[i >> 10];
}

// atomic-free placement: ssrc[rowptr[dst] + pos[e]] = src
__global__ void k_place(const int* __restrict__ ei, int E,
                        const int* __restrict__ rowptr,
                        const int* __restrict__ pos, int* __restrict__ ssrc) {
    int e = blockIdx.x * blockDim.x + threadIdx.x;
    if (e >= E) return;
    int s = ei[e];
    int d = ei[E + e];
    ssrc[rowptr[d] + pos[e]] = s;
}

// A[N,64] = x[N,128] @ W[128,64].  W staged in LDS (32KB), 4 rows/block.
__global__ __launch_bounds__(256) void k_gemm1(const float* __restrict__ x,
                                               const float* __restrict__ W,
                                               float* __restrict__ A, int N) {
    __shared__ float Ws[128 * 64];
    __shared__ float xs[4 * 128];
    for (int i = threadIdx.x; i < 128 * 64; i += 256) Ws[i] = W[i];
    int base = blockIdx.x << 2;
    int t = threadIdx.x;
    if (t < 128) {
        int row = base + (t >> 5);
        if (row < N) {
            float4 v = reinterpret_cast<const float4*>(x)[(size_t)row * 32 + (t & 31)];
            reinterpret_cast<float4*>(xs)[t] = v;
        }
    }
    __syncthreads();
    int ty = t >> 6, col = t & 63;
    float acc = 0.f;
    const float* xr = xs + ty * 128;
#pragma unroll
    for (int k = 0; k < 128; ++k) acc = fmaf(xr[k], Ws[k * 64 + col], acc);
    int row = base + ty;
    if (row < N) A[(size_t)row * 64 + col] = acc;
}

// CSR gather-aggregate: out[d] = f( sum_{s in adj(d)} feat[s]*dinv[s] * dinv[d], other[d] )
// EPI==1: out = relu(agg + other*dinv^2 + bias)   (layer-1 epilogue)
// EPI==2: out = agg + other*dinv^2                (r for the final dual GEMV)
template <int EPI>
__global__ __launch_bounds__(256) void k_aggcsr(const int* __restrict__ rowptr,
                                                const int* __restrict__ ssrc,
                                                const float* __restrict__ dinv,
                                                const float* __restrict__ feat,
                                                const float* __restrict__ other,
                                                const float* __restrict__ bias,
                                                float* __restrict__ out, int N) {
    int idx = blockIdx.x * 256 + threadIdx.x;
    int g = idx >> 4;
    if (g >= N) return;
    int f4 = (idx & 15) << 2;
    int beg = rowptr[g], end = rowptr[g + 1];
    float4 acc = {0.f, 0.f, 0.f, 0.f};
    for (int j = beg; j < end; ++j) {
        int s = ssrc[j];
        float ns = dinv[s];
        float4 v = *reinterpret_cast<const float4*>(feat + (size_t)s * 64 + f4);
        acc.x = fmaf(v.x, ns, acc.x);
        acc.y = fmaf(v.y, ns, acc.y);
        acc.z = fmaf(v.z, ns, acc.z);
        acc.w = fmaf(v.w, ns, acc.w);
    }
    float dd = dinv[g];
    float d2 = dd * dd;
    float4 o = *reinterpret_cast<const float4*>(other + (size_t)g * 64 + f4);
    float4 r;
    if (EPI == 1) {
        float4 bv = *reinterpret_cast<const float4*>(bias + f4);
        r.x = fmaf(acc.x, dd, fmaf(o.x, d2, bv.x));
        r.y = fmaf(acc.y, dd, fmaf(o.y, d2, bv.y));
        r.z = fmaf(acc.z, dd, fmaf(o.z, d2, bv.z));
        r.w = fmaf(acc.w, dd, fmaf(o.w, d2, bv.w));
        r.x = r.x > 0.f ? r.x : 0.f;
        r.y = r.y > 0.f ? r.y : 0.f;
        r.z = r.z > 0.f ? r.z : 0.f;
        r.w = r.w > 0.f ? r.w : 0.f;
    } else {
        r.x = fmaf(acc.x, dd, o.x * d2);
        r.y = fmaf(acc.y, dd, o.y * d2);
        r.z = fmaf(acc.z, dd, o.z * d2);
        r.w = fmaf(acc.w, dd, o.w * d2);
    }
    *reinterpret_cast<float4*>(out + (size_t)g * 64 + f4) = r;
}

// mu = r@Wmu+bmu; log = r@Wlog+blog.  8 rows/block, 32 cols/row; W in LDS.
__global__ __launch_bounds__(256) void k_final(const float* __restrict__ R,
                                               const float* __restrict__ Wmu,
                                               const float* __restrict__ bmu,
                                               const float* __restrict__ Wlg,
                                               const float* __restrict__ blg,
                                               float* __restrict__ out, int N) {
    __shared__ float Wm[64 * 32];
    __shared__ float Wl[64 * 32];
    __shared__ float r[8 * 64];
    for (int i = threadIdx.x; i < 64 * 32; i += 256) {
        Wm[i] = Wmu[i];
        Wl[i] = Wlg[i];
    }
    int base = blockIdx.x << 3;
    int t = threadIdx.x;
    if (t < 128) {
        int row = base + (t >> 4);
        if (row < N) {
            float4 v = reinterpret_cast<const float4*>(R)[(size_t)row * 16 + (t & 15)];
            reinterpret_cast<float4*>(r)[t] = v;
        }
    }
    __syncthreads();
    int ry = t >> 5, c = t & 31;
    float accm = bmu[c], accl = blg[c];
    const float* rr = r + ry * 64;
#pragma unroll
    for (int k = 0; k < 64; ++k) {
        float rv = rr[k];
        accm = fmaf(rv, Wm[k * 32 + c], accm);
        accl = fmaf(rv, Wl[k * 32 + c], accl);
    }
    int row = base + ry;
    if (row < N) {
        out[(size_t)row * 32 + c] = accm;
        out[(size_t)N * 32 + (size_t)row * 32 + c] = accl;
    }
}

extern "C" void kernel_launch(void* const* d_in, const int* in_sizes, int n_in,
                              void* d_out, int out_size, void* d_ws, size_t ws_size,
                              hipStream_t stream) {
    const float* x   = (const float*)d_in[0];
    const int*   ei  = (const int*)d_in[1];   // [2,E] flat: src then dst
    const float* W1  = (const float*)d_in[2];
    const float* b1  = (const float*)d_in[3];
    const float* Wmu = (const float*)d_in[4];
    const float* bmu = (const float*)d_in[5];
    const float* Wlg = (const float*)d_in[6];
    const float* blg = (const float*)d_in[7];
    float* out = (float*)d_out;

    const int N = in_sizes[0] / 128;
    const int E = in_sizes[1] / 2;

    // workspace layout:
    // A[N*64] f32 | B[N*64] f32 | ssrc[E] i32 | deg[N] i32 | rowptr[N+1] i32
    // | dinv[N] f32 | partial[256] i32.   pos[E] ALIASES B (dead until agg<1>).
    float* A       = (float*)d_ws;
    float* B       = A + (size_t)N * 64;
    int*   ssrc    = (int*)(B + (size_t)N * 64);
    int*   deg     = ssrc + E;
    int*   rowptr  = deg + N;
    float* dinv    = (float*)(rowptr + (N + 1));
    int*   partial = (int*)(dinv + N);
    int*   pos     = (int*)B;                 // alias: consumed before B is written

    const int NP = (N + 1023) / 1024;

    hipMemsetAsync(deg, 0, (size_t)N * sizeof(int), stream);

    k_degpos<<<(E + 255) / 256, 256, 0, stream>>>(ei + E, E, deg, pos);
    k_dinv<<<(N + 255) / 256, 256, 0, stream>>>(deg, dinv, N);

    k_scan1<<<NP, 256, 0, stream>>>(deg, rowptr, partial, N);
    k_scan2<<<1, 256, 0, stream>>>(partial, NP, rowptr, N, E);
    k_scan3<<<(N + 255) / 256, 256, 0, stream>>>(rowptr, partial, N);
    k_place<<<(E + 255) / 256, 256, 0, stream>>>(ei, E, rowptr, pos, ssrc);

    k_gemm1<<<(N + 3) / 4, 256, 0, stream>>>(x, W1, A, N);

    // layer 1: B = relu(agg(A) + A*dinv^2 + b1)   (pos dead from here on)
    k_aggcsr<1><<<(int)(((size_t)N * 16 + 255) / 256), 256, 0, stream>>>(
        rowptr, ssrc, dinv, A, A, b1, B, N);
    // layer 2 shared aggregation: A = agg(B) + B*dinv^2   (this is r)
    k_aggcsr<2><<<(int)(((size_t)N * 16 + 255) / 256), 256, 0, stream>>>(
        rowptr, ssrc, dinv, B, B, b1, A, N);

    k_final<<<(N + 7) / 8, 256, 0, stream>>>(A, Wmu, bmu, Wlg, blg, out, N);
}

// Round 4
// 411.885 us; speedup vs baseline: 7.3899x; 1.1303x over previous
//
#include <hip/hip_runtime.h>

// ---------------------------------------------------------------------------
// GCN encoder: mu, log = GCNConv(relu(GCNConv(x,W1,b1)), W_mu/W_log)
// Identity: segment_sum((h@W)[src]*norm) == segment_sum(h[src]*norm) @ W
// R1: CSR + gather (killed f32-atomic write-through).
// R2: one atomic pass (degpos), atomic-free place.
// R3: register-blocked GEMMs (8x4 per thread, W in LDS as b128, x/r in regs)
//     -> FMA-bound; degpos fused with gemm1 (atomics hide the GEMM);
//     pre-scaled features (A2=A*dinv, B2=relu*dinv) -> agg inner loop is
//     pure gather+ADD; dinv folded into scan1; place fused with A-scaling.
// ---------------------------------------------------------------------------

// ---- fused: edge blocks do deg histogram + rank; gemm blocks do A = x@W1 ---
__global__ __launch_bounds__(256) void k_fused1(const int* __restrict__ ei, int E,
                                                int* __restrict__ deg,
                                                int* __restrict__ pos,
                                                const float* __restrict__ x,
                                                const float* __restrict__ W1,
                                                float* __restrict__ A, int N, int EB) {
    __shared__ float Ws[128 * 64];
    int t = threadIdx.x;
    int b = blockIdx.x;
    if (b < EB) {                       // ---- degpos part ----
        int e = b * 256 + t;
        if (e < E) pos[e] = atomicAdd(&deg[ei[E + e]], 1);
        return;
    }
    // ---- gemm part: 128 rows/block, thread = 8 rows x 4 cols ----
    int bb = b - EB;
    for (int i = t; i < 2048; i += 256)
        reinterpret_cast<float4*>(Ws)[i] = reinterpret_cast<const float4*>(W1)[i];
    __syncthreads();
    int cg = t & 15, rg = t >> 4;
    int row0 = bb * 128 + rg * 8;
    int c4 = cg * 4;
    float4 acc[8];
#pragma unroll
    for (int i = 0; i < 8; ++i) acc[i] = {0.f, 0.f, 0.f, 0.f};
    for (int k0 = 0; k0 < 128; k0 += 4) {
        float4 xr[8];
#pragma unroll
        for (int i = 0; i < 8; ++i) {
            int rr = row0 + i;
            if (rr >= N) rr = N - 1;
            xr[i] = *reinterpret_cast<const float4*>(x + (size_t)rr * 128 + k0);
        }
#pragma unroll
        for (int kk = 0; kk < 4; ++kk) {
            float4 w = *reinterpret_cast<const float4*>(Ws + (k0 + kk) * 64 + c4);
#pragma unroll
            for (int i = 0; i < 8; ++i) {
                float xv = (&xr[i].x)[kk];
                acc[i].x = fmaf(xv, w.x, acc[i].x);
                acc[i].y = fmaf(xv, w.y, acc[i].y);
                acc[i].z = fmaf(xv, w.z, acc[i].z);
                acc[i].w = fmaf(xv, w.w, acc[i].w);
            }
        }
    }
#pragma unroll
    for (int i = 0; i < 8; ++i) {
        int rr = row0 + i;
        if (rr < N) *reinterpret_cast<float4*>(A + (size_t)rr * 64 + c4) = acc[i];
    }
}

// ---- two-level exclusive scan of deg[N] -> rowptr[N+1]; dinv fused ----------
__global__ __launch_bounds__(256) void k_scan1(const int* __restrict__ deg,
                                               int* __restrict__ rowptr,
                                               int* __restrict__ partial,
                                               float* __restrict__ dinv, int N) {
    __shared__ int sdata[256];
    int t = threadIdx.x;
    int idx = blockIdx.x * 1024 + t * 4;
    int4 v = {0, 0, 0, 0};
    if (idx + 3 < N) {
        v = *reinterpret_cast<const int4*>(deg + idx);
    } else {
        int* p = (int*)&v;
        for (int k = 0; k < 4; ++k) p[k] = (idx + k < N) ? deg[idx + k] : 0;
    }
    // fused dinv = rsqrt(deg+1)
    if (idx + 3 < N) {
        float4 dv;
        dv.x = rsqrtf((float)(v.x + 1));
        dv.y = rsqrtf((float)(v.y + 1));
        dv.z = rsqrtf((float)(v.z + 1));
        dv.w = rsqrtf((float)(v.w + 1));
        *reinterpret_cast<float4*>(dinv + idx) = dv;
    } else {
        int* p = (int*)&v;
        for (int k = 0; k < 4; ++k)
            if (idx + k < N) dinv[idx + k] = rsqrtf((float)(p[k] + 1));
    }
    int s0 = v.x, s1 = s0 + v.y, s2 = s1 + v.z, s3 = s2 + v.w;
    sdata[t] = s3;
    __syncthreads();
    for (int off = 1; off < 256; off <<= 1) {
        int val = (t >= off) ? sdata[t - off] : 0;
        __syncthreads();
        sdata[t] += val;
        __syncthreads();
    }
    int excl = (t > 0) ? sdata[t - 1] : 0;
    if (t == 255) partial[blockIdx.x] = sdata[255];
    int4 o;
    o.x = excl; o.y = excl + s0; o.z = excl + s1; o.w = excl + s2;
    if (idx + 3 < N) {
        *reinterpret_cast<int4*>(rowptr + idx) = o;
    } else {
        int* p = (int*)&o;
        for (int k = 0; k < 4; ++k) if (idx + k < N) rowptr[idx + k] = p[k];
    }
}

__global__ __launch_bounds__(256) void k_scan2(int* __restrict__ partial, int NP,
                                               int* __restrict__ rowptr, int N, int E) {
    __shared__ int sdata[256];
    int t = threadIdx.x;
    int val = (t < NP) ? partial[t] : 0;
    sdata[t] = val;
    __syncthreads();
    for (int off = 1; off < 256; off <<= 1) {
        int v2 = (t >= off) ? sdata[t - off] : 0;
        __syncthreads();
        sdata[t] += v2;
        __syncthreads();
    }
    if (t < NP) partial[t] = sdata[t] - val;   // exclusive
    if (t == 0) rowptr[N] = E;
}

__global__ void k_scan3(int* __restrict__ rowptr, const int* __restrict__ partial, int N) {
    int i = blockIdx.x * blockDim.x + threadIdx.x;
    if (i < N) rowptr[i] += partial[i >> 10];
}

// ---- fused: place blocks scatter ssrc; scale blocks do A *= dinv[row] ------
__global__ void k_fused2(const int* __restrict__ ei, int E,
                         const int* __restrict__ rowptr,
                         const int* __restrict__ pos,
                         int* __restrict__ ssrc,
                         float* __restrict__ A,
                         const float* __restrict__ dinv, int N, int EB) {
    int b = blockIdx.x, t = threadIdx.x;
    if (b < EB) {                       // ---- place part ----
        int e = b * 256 + t;
        if (e < E) ssrc[rowptr[ei[E + e]] + pos[e]] = ei[e];
        return;
    }
    // ---- scale part: one float4 per thread over N*16 ----
    int idx = (b - EB) * 256 + t;
    if (idx >= N * 16) return;
    int row = idx >> 4;
    float dd = dinv[row];
    float4* p = reinterpret_cast<float4*>(A) + idx;
    float4 v = *p;
    v.x *= dd; v.y *= dd; v.z *= dd; v.w *= dd;
    *p = v;
}

// CSR gather of pre-scaled features (feat2 = feat*dinv), self term in init.
// EPI==1: out = relu((sum)*dd + bias) * dd     (B2 for layer 2)
// EPI==2: out = (sum)*dd                       (r for the final dual GEMV)
template <int EPI>
__global__ __launch_bounds__(256) void k_agg(const int* __restrict__ rowptr,
                                             const int* __restrict__ ssrc,
                                             const float* __restrict__ dinv,
                                             const float* __restrict__ feat2,
                                             const float* __restrict__ bias,
                                             float* __restrict__ out, int N) {
    int idx = blockIdx.x * 256 + threadIdx.x;
    int g = idx >> 4;
    if (g >= N) return;
    int f4 = (idx & 15) << 2;
    int beg = rowptr[g], end = rowptr[g + 1];
    float4 acc = *reinterpret_cast<const float4*>(feat2 + (size_t)g * 64 + f4); // self
    for (int j = beg; j < end; ++j) {
        int s = ssrc[j];
        float4 v = *reinterpret_cast<const float4*>(feat2 + (size_t)s * 64 + f4);
        acc.x += v.x; acc.y += v.y; acc.z += v.z; acc.w += v.w;
    }
    float dd = dinv[g];
    float4 r;
    if (EPI == 1) {
        float4 bv = *reinterpret_cast<const float4*>(bias + f4);
        r.x = fmaf(acc.x, dd, bv.x);
        r.y = fmaf(acc.y, dd, bv.y);
        r.z = fmaf(acc.z, dd, bv.z);
        r.w = fmaf(acc.w, dd, bv.w);
        r.x = r.x > 0.f ? r.x * dd : 0.f;
        r.y = r.y > 0.f ? r.y * dd : 0.f;
        r.z = r.z > 0.f ? r.z * dd : 0.f;
        r.w = r.w > 0.f ? r.w * dd : 0.f;
    } else {
        r.x = acc.x * dd; r.y = acc.y * dd; r.z = acc.z * dd; r.w = acc.w * dd;
    }
    *reinterpret_cast<float4*>(out + (size_t)g * 64 + f4) = r;
}

// Final dual GEMV, register-blocked like gemm1: 128 rows/block, 8x4/thread.
// Wboth[64][64] = [Wmu | Wlg] staged in LDS; r rows from global into regs.
__global__ __launch_bounds__(256) void k_final2(const float* __restrict__ R,
                                                const float* __restrict__ Wmu,
                                                const float* __restrict__ bmu,
                                                const float* __restrict__ Wlg,
                                                const float* __restrict__ blg,
                                                float* __restrict__ out, int N) {
    __shared__ float Ws[64 * 64];
    int t = threadIdx.x;
    for (int i = t; i < 4096; i += 256) {
        int k = i >> 6, c = i & 63;
        Ws[i] = (c < 32) ? Wmu[(k << 5) + c] : Wlg[(k << 5) + (c - 32)];
    }
    __syncthreads();
    int cg = t & 15, rg = t >> 4;
    int row0 = blockIdx.x * 128 + rg * 8;
    int c4 = cg * 4;
    float4 bv;
    if (c4 < 32) bv = *reinterpret_cast<const float4*>(bmu + c4);
    else         bv = *reinterpret_cast<const float4*>(blg + c4 - 32);
    float4 acc[8];
#pragma unroll
    for (int i = 0; i < 8; ++i) acc[i] = bv;
    for (int k0 = 0; k0 < 64; k0 += 4) {
        float4 xr[8];
#pragma unroll
        for (int i = 0; i < 8; ++i) {
            int rr = row0 + i;
            if (rr >= N) rr = N - 1;
            xr[i] = *reinterpret_cast<const float4*>(R + (size_t)rr * 64 + k0);
        }
#pragma unroll
        for (int kk = 0; kk < 4; ++kk) {
            float4 w = *reinterpret_cast<const float4*>(Ws + (k0 + kk) * 64 + c4);
#pragma unroll
            for (int i = 0; i < 8; ++i) {
                float xv = (&xr[i].x)[kk];
                acc[i].x = fmaf(xv, w.x, acc[i].x);
                acc[i].y = fmaf(xv, w.y, acc[i].y);
                acc[i].z = fmaf(xv, w.z, acc[i].z);
                acc[i].w = fmaf(xv, w.w, acc[i].w);
            }
        }
    }
#pragma unroll
    for (int i = 0; i < 8; ++i) {
        int rr = row0 + i;
        if (rr < N) {
            float* dst = (c4 < 32) ? (out + (size_t)rr * 32 + c4)
                                   : (out + (size_t)N * 32 + (size_t)rr * 32 + (c4 - 32));
            *reinterpret_cast<float4*>(dst) = acc[i];
        }
    }
}

extern "C" void kernel_launch(void* const* d_in, const int* in_sizes, int n_in,
                              void* d_out, int out_size, void* d_ws, size_t ws_size,
                              hipStream_t stream) {
    const float* x   = (const float*)d_in[0];
    const int*   ei  = (const int*)d_in[1];   // [2,E] flat: src then dst
    const float* W1  = (const float*)d_in[2];
    const float* b1  = (const float*)d_in[3];
    const float* Wmu = (const float*)d_in[4];
    const float* bmu = (const float*)d_in[5];
    const float* Wlg = (const float*)d_in[6];
    const float* blg = (const float*)d_in[7];
    float* out = (float*)d_out;

    const int N = in_sizes[0] / 128;
    const int E = in_sizes[1] / 2;

    // workspace: A[N*64] | B[N*64] | ssrc[E] | deg[N] | rowptr[N+1] | dinv[N]
    // | partial[256].   pos[E] ALIASES B (dead before agg<1> writes B).
    float* A       = (float*)d_ws;
    float* B       = A + (size_t)N * 64;
    int*   ssrc    = (int*)(B + (size_t)N * 64);
    int*   deg     = ssrc + E;
    int*   rowptr  = deg + N;
    float* dinv    = (float*)(rowptr + (N + 1));
    int*   partial = (int*)(dinv + N);
    int*   pos     = (int*)B;

    const int NP  = (N + 1023) / 1024;       // scan partials (<=256)
    const int EB  = (E + 255) / 256;         // edge blocks
    const int GB  = (N + 127) / 128;         // gemm blocks (128 rows each)
    const int SB  = (N * 16 + 255) / 256;    // scale blocks
    const int AB  = (int)(((size_t)N * 16 + 255) / 256);

    hipMemsetAsync(deg, 0, (size_t)N * sizeof(int), stream);

    // degpos (atomics) runs in parallel with the x@W1 GEMM
    k_fused1<<<EB + GB, 256, 0, stream>>>(ei, E, deg, pos, x, W1, A, N, EB);

    k_scan1<<<NP, 256, 0, stream>>>(deg, rowptr, partial, dinv, N);
    k_scan2<<<1, 256, 0, stream>>>(partial, NP, rowptr, N, E);
    k_scan3<<<(N + 255) / 256, 256, 0, stream>>>(rowptr, partial, N);

    // place (atomic-free scatter) runs in parallel with A *= dinv scaling
    k_fused2<<<EB + SB, 256, 0, stream>>>(ei, E, rowptr, pos, ssrc, A, dinv, N, EB);

    // layer 1: B2 = relu(agg(A2)*dd + b1) * dd
    k_agg<1><<<AB, 256, 0, stream>>>(rowptr, ssrc, dinv, A, b1, B, N);
    // layer 2 shared aggregation: A = r = agg(B2)*dd
    k_agg<2><<<AB, 256, 0, stream>>>(rowptr, ssrc, dinv, B, b1, A, N);

    k_final2<<<GB, 256, 0, stream>>>(A, Wmu, bmu, Wlg, blg, out, N);
}

// Round 5
// 405.643 us; speedup vs baseline: 7.5036x; 1.0154x over previous
//
#include <hip/hip_runtime.h>

// ---------------------------------------------------------------------------
// GCN encoder: mu, log = GCNConv(relu(GCNConv(x,W1,b1)), W_mu/W_log)
// Identity: segment_sum((h@W)[src]*norm) == segment_sum(h[src]*norm) @ W
// R1: CSR + gather (killed f32-atomic write-through).
// R2: one atomic pass (degpos), atomic-free place.
// R3: register-blocked GEMMs; degpos||gemm fusion; pre-scaled features.
// R4: XCD-sharded histogram: cnt[8][N], edge block b atomics into shard b&7
//     (blocks round-robin across XCDs -> shard lines stay in ONE XCD's L2,
//     no cross-XCD line ping-pong). scan1 builds per-node shard prefixes
//     in place; scan3 folds rowptr in so cnt[c][i] = absolute CSR base.
//     1-ahead ssrc prefetch in the agg gather loop.
// ---------------------------------------------------------------------------

// ---- fused: edge blocks do sharded histogram + rank; gemm blocks A = x@W1 --
__global__ __launch_bounds__(256) void k_fused1(const int* __restrict__ ei, int E,
                                                int* __restrict__ cnt,
                                                int* __restrict__ pos,
                                                const float* __restrict__ x,
                                                const float* __restrict__ W1,
                                                float* __restrict__ A, int N, int EB) {
    __shared__ float Ws[128 * 64];
    int t = threadIdx.x;
    int b = blockIdx.x;
    if (b < EB) {                       // ---- sharded degpos ----
        int e = b * 256 + t;
        if (e < E) pos[e] = atomicAdd(&cnt[(size_t)(b & 7) * N + ei[E + e]], 1);
        return;
    }
    // ---- gemm part: 128 rows/block, thread = 8 rows x 4 cols ----
    int bb = b - EB;
    for (int i = t; i < 2048; i += 256)
        reinterpret_cast<float4*>(Ws)[i] = reinterpret_cast<const float4*>(W1)[i];
    __syncthreads();
    int cg = t & 15, rg = t >> 4;
    int row0 = bb * 128 + rg * 8;
    int c4 = cg * 4;
    float4 acc[8];
#pragma unroll
    for (int i = 0; i < 8; ++i) acc[i] = {0.f, 0.f, 0.f, 0.f};
    for (int k0 = 0; k0 < 128; k0 += 4) {
        float4 xr[8];
#pragma unroll
        for (int i = 0; i < 8; ++i) {
            int rr = row0 + i;
            if (rr >= N) rr = N - 1;
            xr[i] = *reinterpret_cast<const float4*>(x + (size_t)rr * 128 + k0);
        }
#pragma unroll
        for (int kk = 0; kk < 4; ++kk) {
            float4 w = *reinterpret_cast<const float4*>(Ws + (k0 + kk) * 64 + c4);
#pragma unroll
            for (int i = 0; i < 8; ++i) {
                float xv = (&xr[i].x)[kk];
                acc[i].x = fmaf(xv, w.x, acc[i].x);
                acc[i].y = fmaf(xv, w.y, acc[i].y);
                acc[i].z = fmaf(xv, w.z, acc[i].z);
                acc[i].w = fmaf(xv, w.w, acc[i].w);
            }
        }
    }
#pragma unroll
    for (int i = 0; i < 8; ++i) {
        int rr = row0 + i;
        if (rr < N) *reinterpret_cast<float4*>(A + (size_t)rr * 64 + c4) = acc[i];
    }
}

// ---- scan1: per-node shard prefix (in place) + deg total -> block scan;
//      dinv = rsqrt(deg+1) fused ------------------------------------------------
__global__ __launch_bounds__(256) void k_scan1(int* __restrict__ cnt,
                                               int* __restrict__ rowptr,
                                               int* __restrict__ partial,
                                               float* __restrict__ dinv, int N) {
    __shared__ int sdata[256];
    int t = threadIdx.x;
    int idx = blockIdx.x * 1024 + t * 4;
    int4 tot = {0, 0, 0, 0};
    if (idx + 3 < N) {
        int4 run = {0, 0, 0, 0};
#pragma unroll
        for (int s = 0; s < 8; ++s) {
            int4* p = reinterpret_cast<int4*>(cnt + (size_t)s * N + idx);
            int4 cs = *p;
            *p = run;                                  // shard-exclusive prefix
            run.x += cs.x; run.y += cs.y; run.z += cs.z; run.w += cs.w;
        }
        tot = run;
        float4 dv;
        dv.x = rsqrtf((float)(tot.x + 1));
        dv.y = rsqrtf((float)(tot.y + 1));
        dv.z = rsqrtf((float)(tot.z + 1));
        dv.w = rsqrtf((float)(tot.w + 1));
        *reinterpret_cast<float4*>(dinv + idx) = dv;
    } else {
        int* tp = (int*)&tot;
        for (int k = 0; k < 4; ++k) {
            if (idx + k < N) {
                int run = 0;
                for (int s = 0; s < 8; ++s) {
                    int* p = cnt + (size_t)s * N + idx + k;
                    int cs = *p; *p = run; run += cs;
                }
                tp[k] = run;
                dinv[idx + k] = rsqrtf((float)(run + 1));
            }
        }
    }
    int s0 = tot.x, s1 = s0 + tot.y, s2 = s1 + tot.z, s3 = s2 + tot.w;
    sdata[t] = s3;
    __syncthreads();
    for (int off = 1; off < 256; off <<= 1) {
        int val = (t >= off) ? sdata[t - off] : 0;
        __syncthreads();
        sdata[t] += val;
        __syncthreads();
    }
    int excl = (t > 0) ? sdata[t - 1] : 0;
    if (t == 255) partial[blockIdx.x] = sdata[255];
    int4 o;
    o.x = excl; o.y = excl + s0; o.z = excl + s1; o.w = excl + s2;
    if (idx + 3 < N) {
        *reinterpret_cast<int4*>(rowptr + idx) = o;
    } else {
        int* p = (int*)&o;
        for (int k = 0; k < 4; ++k) if (idx + k < N) rowptr[idx + k] = p[k];
    }
}

__global__ __launch_bounds__(256) void k_scan2(int* __restrict__ partial, int NP,
                                               int* __restrict__ rowptr, int N, int E) {
    __shared__ int sdata[256];
    int t = threadIdx.x;
    int val = (t < NP) ? partial[t] : 0;
    sdata[t] = val;
    __syncthreads();
    for (int off = 1; off < 256; off <<= 1) {
        int v2 = (t >= off) ? sdata[t - off] : 0;
        __syncthreads();
        sdata[t] += v2;
        __syncthreads();
    }
    if (t < NP) partial[t] = sdata[t] - val;   // exclusive
    if (t == 0) rowptr[N] = E;
}

// scan3: finalize rowptr AND turn cnt[c][i] into absolute CSR base
__global__ void k_scan3(int* __restrict__ rowptr, const int* __restrict__ partial,
                        int* __restrict__ cnt, int N) {
    int i = blockIdx.x * blockDim.x + threadIdx.x;
    if (i >= N) return;
    int rp = rowptr[i] + partial[i >> 10];
    rowptr[i] = rp;
#pragma unroll
    for (int s = 0; s < 8; ++s) cnt[(size_t)s * N + i] += rp;
}

// ---- fused: place blocks scatter ssrc (atomic-free); scale blocks A*=dinv --
__global__ void k_fused2(const int* __restrict__ ei, int E,
                         const int* __restrict__ cnt,
                         const int* __restrict__ pos,
                         int* __restrict__ ssrc,
                         float* __restrict__ A,
                         const float* __restrict__ dinv, int N, int EB) {
    int b = blockIdx.x, t = threadIdx.x;
    if (b < EB) {                       // ---- place part ----
        int e = b * 256 + t;
        if (e < E) {
            int src = ei[e];
            int d   = ei[E + e];
            ssrc[cnt[(size_t)(b & 7) * N + d] + pos[e]] = src;
        }
        return;
    }
    // ---- scale part: one float4 per thread over N*16 ----
    int idx = (b - EB) * 256 + t;
    if (idx >= N * 16) return;
    int row = idx >> 4;
    float dd = dinv[row];
    float4* p = reinterpret_cast<float4*>(A) + idx;
    float4 v = *p;
    v.x *= dd; v.y *= dd; v.z *= dd; v.w *= dd;
    *p = v;
}

// CSR gather of pre-scaled features (feat2 = feat*dinv), self term in init.
// EPI==1: out = relu((sum)*dd + bias) * dd     (B2 for layer 2)
// EPI==2: out = (sum)*dd                       (r for the final dual GEMV)
template <int EPI>
__global__ __launch_bounds__(256) void k_agg(const int* __restrict__ rowptr,
                                             const int* __restrict__ ssrc,
                                             const float* __restrict__ dinv,
                                             const float* __restrict__ feat2,
                                             const float* __restrict__ bias,
                                             float* __restrict__ out, int N) {
    int idx = blockIdx.x * 256 + threadIdx.x;
    int g = idx >> 4;
    if (g >= N) return;
    int f4 = (idx & 15) << 2;
    int beg = rowptr[g], end = rowptr[g + 1];
    float4 acc = *reinterpret_cast<const float4*>(feat2 + (size_t)g * 64 + f4); // self
    int j = beg;
    int snext = (j < end) ? ssrc[j] : 0;
    while (j < end) {
        int scur = snext;
        ++j;
        if (j < end) snext = ssrc[j];           // 1-ahead: break idx->gather chain
        float4 v = *reinterpret_cast<const float4*>(feat2 + (size_t)scur * 64 + f4);
        acc.x += v.x; acc.y += v.y; acc.z += v.z; acc.w += v.w;
    }
    float dd = dinv[g];
    float4 r;
    if (EPI == 1) {
        float4 bv = *reinterpret_cast<const float4*>(bias + f4);
        r.x = fmaf(acc.x, dd, bv.x);
        r.y = fmaf(acc.y, dd, bv.y);
        r.z = fmaf(acc.z, dd, bv.z);
        r.w = fmaf(acc.w, dd, bv.w);
        r.x = r.x > 0.f ? r.x * dd : 0.f;
        r.y = r.y > 0.f ? r.y * dd : 0.f;
        r.z = r.z > 0.f ? r.z * dd : 0.f;
        r.w = r.w > 0.f ? r.w * dd : 0.f;
    } else {
        r.x = acc.x * dd; r.y = acc.y * dd; r.z = acc.z * dd; r.w = acc.w * dd;
    }
    *reinterpret_cast<float4*>(out + (size_t)g * 64 + f4) = r;
}

// Final dual GEMV, register-blocked: 128 rows/block, 8x4/thread.
// Ws[64][64] = [Wmu | Wlg] in LDS; r rows from global into regs.
__global__ __launch_bounds__(256) void k_final2(const float* __restrict__ R,
                                                const float* __restrict__ Wmu,
                                                const float* __restrict__ bmu,
                                                const float* __restrict__ Wlg,
                                                const float* __restrict__ blg,
                                                float* __restrict__ out, int N) {
    __shared__ float Ws[64 * 64];
    int t = threadIdx.x;
    for (int i = t; i < 4096; i += 256) {
        int k = i >> 6, c = i & 63;
        Ws[i] = (c < 32) ? Wmu[(k << 5) + c] : Wlg[(k << 5) + (c - 32)];
    }
    __syncthreads();
    int cg = t & 15, rg = t >> 4;
    int row0 = blockIdx.x * 128 + rg * 8;
    int c4 = cg * 4;
    float4 bv;
    if (c4 < 32) bv = *reinterpret_cast<const float4*>(bmu + c4);
    else         bv = *reinterpret_cast<const float4*>(blg + c4 - 32);
    float4 acc[8];
#pragma unroll
    for (int i = 0; i < 8; ++i) acc[i] = bv;
    for (int k0 = 0; k0 < 64; k0 += 4) {
        float4 xr[8];
#pragma unroll
        for (int i = 0; i < 8; ++i) {
            int rr = row0 + i;
            if (rr >= N) rr = N - 1;
            xr[i] = *reinterpret_cast<const float4*>(R + (size_t)rr * 64 + k0);
        }
#pragma unroll
        for (int kk = 0; kk < 4; ++kk) {
            float4 w = *reinterpret_cast<const float4*>(Ws + (k0 + kk) * 64 + c4);
#pragma unroll
            for (int i = 0; i < 8; ++i) {
                float xv = (&xr[i].x)[kk];
                acc[i].x = fmaf(xv, w.x, acc[i].x);
                acc[i].y = fmaf(xv, w.y, acc[i].y);
                acc[i].z = fmaf(xv, w.z, acc[i].z);
                acc[i].w = fmaf(xv, w.w, acc[i].w);
            }
        }
    }
#pragma unroll
    for (int i = 0; i < 8; ++i) {
        int rr = row0 + i;
        if (rr < N) {
            float* dst = (c4 < 32) ? (out + (size_t)rr * 32 + c4)
                                   : (out + (size_t)N * 32 + (size_t)rr * 32 + (c4 - 32));
            *reinterpret_cast<float4*>(dst) = acc[i];
        }
    }
}

extern "C" void kernel_launch(void* const* d_in, const int* in_sizes, int n_in,
                              void* d_out, int out_size, void* d_ws, size_t ws_size,
                              hipStream_t stream) {
    const float* x   = (const float*)d_in[0];
    const int*   ei  = (const int*)d_in[1];   // [2,E] flat: src then dst
    const float* W1  = (const float*)d_in[2];
    const float* b1  = (const float*)d_in[3];
    const float* Wmu = (const float*)d_in[4];
    const float* bmu = (const float*)d_in[5];
    const float* Wlg = (const float*)d_in[6];
    const float* blg = (const float*)d_in[7];
    float* out = (float*)d_out;

    const int N = in_sizes[0] / 128;
    const int E = in_sizes[1] / 2;

    // workspace: A[N*64] | B[N*64] | ssrc[E] | cnt[8*N] | rowptr[N+1]
    // | dinv[N] | partial[256].   pos[E] ALIASES B (dead before agg<1>).
    float* A       = (float*)d_ws;
    float* B       = A + (size_t)N * 64;
    int*   ssrc    = (int*)(B + (size_t)N * 64);
    int*   cnt     = ssrc + E;
    int*   rowptr  = cnt + (size_t)8 * N;
    float* dinv    = (float*)(rowptr + (N + 1));
    int*   partial = (int*)(dinv + N);
    int*   pos     = (int*)B;

    const int NP  = (N + 1023) / 1024;       // scan partials (<=256)
    const int EB  = (E + 255) / 256;         // edge blocks
    const int GB  = (N + 127) / 128;         // gemm blocks (128 rows each)
    const int SB  = (N * 16 + 255) / 256;    // scale blocks
    const int AB  = (int)(((size_t)N * 16 + 255) / 256);

    hipMemsetAsync(cnt, 0, (size_t)8 * N * sizeof(int), stream);

    // sharded degpos (atomics, XCD-local) runs in parallel with the x@W1 GEMM
    k_fused1<<<EB + GB, 256, 0, stream>>>(ei, E, cnt, pos, x, W1, A, N, EB);

    k_scan1<<<NP, 256, 0, stream>>>(cnt, rowptr, partial, dinv, N);
    k_scan2<<<1, 256, 0, stream>>>(partial, NP, rowptr, N, E);
    k_scan3<<<(N + 255) / 256, 256, 0, stream>>>(rowptr, partial, cnt, N);

    // place (atomic-free scatter) runs in parallel with A *= dinv scaling
    k_fused2<<<EB + SB, 256, 0, stream>>>(ei, E, cnt, pos, ssrc, A, dinv, N, EB);

    // layer 1: B2 = relu(agg(A2)*dd + b1) * dd
    k_agg<1><<<AB, 256, 0, stream>>>(rowptr, ssrc, dinv, A, b1, B, N);
    // layer 2 shared aggregation: A = r = agg(B2)*dd
    k_agg<2><<<AB, 256, 0, stream>>>(rowptr, ssrc, dinv, B, b1, A, N);

    k_final2<<<GB, 256, 0, stream>>>(A, Wmu, bmu, Wlg, blg, out, N);
}

// Round 7
// 388.368 us; speedup vs baseline: 7.8373x; 1.0445x over previous
//
#include <hip/hip_runtime.h>

// ---------------------------------------------------------------------------
// GCN encoder: mu, log = GCNConv(relu(GCNConv(x,W1,b1)), W_mu/W_log)
// Identity: segment_sum((h@W)[src]*norm) == segment_sum(h[src]*norm) @ W
// R1: CSR + gather (killed f32-atomic write-through).
// R2: one atomic pass (degpos), atomic-free place.
// R3: register-blocked GEMMs; degpos||gemm fusion; pre-scaled features.
// R4: XCD-sharded histogram -> FALSIFIED (no delta). Reverted.
// R5: MLP batching — 4 edges/thread in degpos & place (int4 IO, 4 atomics
//     in flight); agg inner loop unrolled x4 with independent accumulators
//     (4 outstanding 64B gathers per dst-group instead of 1).
// R6: resubmit of R5 (GPU acquisition timeout — no measurement happened).
// ---------------------------------------------------------------------------

// ---- fused: edge blocks (4 edges/thread) do histogram+rank; gemm blocks A=x@W1
__global__ __launch_bounds__(256) void k_fused1(const int* __restrict__ ei, int E,
                                                int* __restrict__ deg,
                                                int* __restrict__ pos,
                                                const float* __restrict__ x,
                                                const float* __restrict__ W1,
                                                float* __restrict__ A, int N, int EB) {
    __shared__ float Ws[128 * 64];
    int t = threadIdx.x;
    int b = blockIdx.x;
    if (b < EB) {                       // ---- degpos: 4 edges per thread ----
        int e0 = b * 1024 + t * 4;
        if (e0 + 3 < E && ((E & 3) == 0)) {
            int4 d4 = *reinterpret_cast<const int4*>(ei + E + e0);
            int4 p4;
            p4.x = atomicAdd(&deg[d4.x], 1);
            p4.y = atomicAdd(&deg[d4.y], 1);
            p4.z = atomicAdd(&deg[d4.z], 1);
            p4.w = atomicAdd(&deg[d4.w], 1);
            *reinterpret_cast<int4*>(pos + e0) = p4;
        } else {
            for (int k = 0; k < 4; ++k) {
                int e = e0 + k;
                if (e < E) pos[e] = atomicAdd(&deg[ei[E + e]], 1);
            }
        }
        return;
    }
    // ---- gemm part: 128 rows/block, thread = 8 rows x 4 cols ----
    int bb = b - EB;
    for (int i = t; i < 2048; i += 256)
        reinterpret_cast<float4*>(Ws)[i] = reinterpret_cast<const float4*>(W1)[i];
    __syncthreads();
    int cg = t & 15, rg = t >> 4;
    int row0 = bb * 128 + rg * 8;
    int c4 = cg * 4;
    float4 acc[8];
#pragma unroll
    for (int i = 0; i < 8; ++i) acc[i] = {0.f, 0.f, 0.f, 0.f};
    for (int k0 = 0; k0 < 128; k0 += 4) {
        float4 xr[8];
#pragma unroll
        for (int i = 0; i < 8; ++i) {
            int rr = row0 + i;
            if (rr >= N) rr = N - 1;
            xr[i] = *reinterpret_cast<const float4*>(x + (size_t)rr * 128 + k0);
        }
#pragma unroll
        for (int kk = 0; kk < 4; ++kk) {
            float4 w = *reinterpret_cast<const float4*>(Ws + (k0 + kk) * 64 + c4);
#pragma unroll
            for (int i = 0; i < 8; ++i) {
                float xv = (&xr[i].x)[kk];
                acc[i].x = fmaf(xv, w.x, acc[i].x);
                acc[i].y = fmaf(xv, w.y, acc[i].y);
                acc[i].z = fmaf(xv, w.z, acc[i].z);
                acc[i].w = fmaf(xv, w.w, acc[i].w);
            }
        }
    }
#pragma unroll
    for (int i = 0; i < 8; ++i) {
        int rr = row0 + i;
        if (rr < N) *reinterpret_cast<float4*>(A + (size_t)rr * 64 + c4) = acc[i];
    }
}

// ---- scan1: block-exclusive scan of deg (1024/block) + dinv = rsqrt(deg+1) --
__global__ __launch_bounds__(256) void k_scan1(const int* __restrict__ deg,
                                               int* __restrict__ rowptr,
                                               int* __restrict__ partial,
                                               float* __restrict__ dinv, int N) {
    __shared__ int sdata[256];
    int t = threadIdx.x;
    int idx = blockIdx.x * 1024 + t * 4;
    int4 v = {0, 0, 0, 0};
    if (idx + 3 < N) {
        v = *reinterpret_cast<const int4*>(deg + idx);
        float4 dv;
        dv.x = rsqrtf((float)(v.x + 1));
        dv.y = rsqrtf((float)(v.y + 1));
        dv.z = rsqrtf((float)(v.z + 1));
        dv.w = rsqrtf((float)(v.w + 1));
        *reinterpret_cast<float4*>(dinv + idx) = dv;
    } else {
        int* p = (int*)&v;
        for (int k = 0; k < 4; ++k) {
            if (idx + k < N) {
                p[k] = deg[idx + k];
                dinv[idx + k] = rsqrtf((float)(p[k] + 1));
            } else p[k] = 0;
        }
    }
    int s0 = v.x, s1 = s0 + v.y, s2 = s1 + v.z, s3 = s2 + v.w;
    sdata[t] = s3;
    __syncthreads();
    for (int off = 1; off < 256; off <<= 1) {
        int val = (t >= off) ? sdata[t - off] : 0;
        __syncthreads();
        sdata[t] += val;
        __syncthreads();
    }
    int excl = (t > 0) ? sdata[t - 1] : 0;
    if (t == 255) partial[blockIdx.x] = sdata[255];
    int4 o;
    o.x = excl; o.y = excl + s0; o.z = excl + s1; o.w = excl + s2;
    if (idx + 3 < N) {
        *reinterpret_cast<int4*>(rowptr + idx) = o;
    } else {
        int* p = (int*)&o;
        for (int k = 0; k < 4; ++k) if (idx + k < N) rowptr[idx + k] = p[k];
    }
}

__global__ __launch_bounds__(256) void k_scan2(int* __restrict__ partial, int NP,
                                               int* __restrict__ rowptr, int N, int E) {
    __shared__ int sdata[256];
    int t = threadIdx.x;
    int val = (t < NP) ? partial[t] : 0;
    sdata[t] = val;
    __syncthreads();
    for (int off = 1; off < 256; off <<= 1) {
        int v2 = (t >= off) ? sdata[t - off] : 0;
        __syncthreads();
        sdata[t] += v2;
        __syncthreads();
    }
    if (t < NP) partial[t] = sdata[t] - val;   // exclusive
    if (t == 0) rowptr[N] = E;
}

__global__ void k_scan3(int* __restrict__ rowptr, const int* __restrict__ partial, int N) {
    int i = blockIdx.x * blockDim.x + threadIdx.x;
    if (i < N) rowptr[i] += partial[i >> 10];
}

// ---- fused: place blocks (4 edges/thread, atomic-free); scale blocks A*=dinv
__global__ void k_fused2(const int* __restrict__ ei, int E,
                         const int* __restrict__ rowptr,
                         const int* __restrict__ pos,
                         int* __restrict__ ssrc,
                         float* __restrict__ A,
                         const float* __restrict__ dinv, int N, int EB) {
    int b = blockIdx.x, t = threadIdx.x;
    if (b < EB) {                       // ---- place: 4 edges per thread ----
        int e0 = b * 1024 + t * 4;
        if (e0 + 3 < E && ((E & 3) == 0)) {
            int4 s4 = *reinterpret_cast<const int4*>(ei + e0);
            int4 d4 = *reinterpret_cast<const int4*>(ei + E + e0);
            int4 p4 = *reinterpret_cast<const int4*>(pos + e0);
            int r0 = rowptr[d4.x];
            int r1 = rowptr[d4.y];
            int r2 = rowptr[d4.z];
            int r3 = rowptr[d4.w];
            ssrc[r0 + p4.x] = s4.x;
            ssrc[r1 + p4.y] = s4.y;
            ssrc[r2 + p4.z] = s4.z;
            ssrc[r3 + p4.w] = s4.w;
        } else {
            for (int k = 0; k < 4; ++k) {
                int e = e0 + k;
                if (e < E) ssrc[rowptr[ei[E + e]] + pos[e]] = ei[e];
            }
        }
        return;
    }
    // ---- scale part: one float4 per thread over N*16 ----
    int idx = (b - EB) * 256 + t;
    if (idx >= N * 16) return;
    int row = idx >> 4;
    float dd = dinv[row];
    float4* p = reinterpret_cast<float4*>(A) + idx;
    float4 v = *p;
    v.x *= dd; v.y *= dd; v.z *= dd; v.w *= dd;
    *p = v;
}

// CSR gather of pre-scaled features, unrolled x4 (4 outstanding gathers).
// EPI==1: out = relu((sum)*dd + bias) * dd     (B2 for layer 2)
// EPI==2: out = (sum)*dd                       (r for the final dual GEMV)
template <int EPI>
__global__ __launch_bounds__(256) void k_agg(const int* __restrict__ rowptr,
                                             const int* __restrict__ ssrc,
                                             const float* __restrict__ dinv,
                                             const float* __restrict__ feat2,
                                             const float* __restrict__ bias,
                                             float* __restrict__ out, int N) {
    int idx = blockIdx.x * 256 + threadIdx.x;
    int g = idx >> 4;
    if (g >= N) return;
    int fo = idx & 15;                           // float4 offset within row
    const float4* F = reinterpret_cast<const float4*>(feat2);
    int beg = rowptr[g], end = rowptr[g + 1];
    float4 a0 = F[(size_t)g * 16 + fo];          // self term
    float4 a1 = {0.f, 0.f, 0.f, 0.f};
    float4 a2 = {0.f, 0.f, 0.f, 0.f};
    float4 a3 = {0.f, 0.f, 0.f, 0.f};
    int j = beg;
    for (; j + 4 <= end; j += 4) {
        int s0 = ssrc[j], s1 = ssrc[j + 1], s2 = ssrc[j + 2], s3 = ssrc[j + 3];
        float4 v0 = F[(size_t)s0 * 16 + fo];
        float4 v1 = F[(size_t)s1 * 16 + fo];
        float4 v2 = F[(size_t)s2 * 16 + fo];
        float4 v3 = F[(size_t)s3 * 16 + fo];
        a0.x += v0.x; a0.y += v0.y; a0.z += v0.z; a0.w += v0.w;
        a1.x += v1.x; a1.y += v1.y; a1.z += v1.z; a1.w += v1.w;
        a2.x += v2.x; a2.y += v2.y; a2.z += v2.z; a2.w += v2.w;
        a3.x += v3.x; a3.y += v3.y; a3.z += v3.z; a3.w += v3.w;
    }
    for (; j < end; ++j) {
        float4 v = F[(size_t)ssrc[j] * 16 + fo];
        a1.x += v.x; a1.y += v.y; a1.z += v.z; a1.w += v.w;
    }
    float4 acc;
    acc.x = (a0.x + a1.x) + (a2.x + a3.x);
    acc.y = (a0.y + a1.y) + (a2.y + a3.y);
    acc.z = (a0.z + a1.z) + (a2.z + a3.z);
    acc.w = (a0.w + a1.w) + (a2.w + a3.w);
    float dd = dinv[g];
    float4 r;
    if (EPI == 1) {
        const float4 bv = *reinterpret_cast<const float4*>(bias + (fo << 2));
        r.x = fmaf(acc.x, dd, bv.x);
        r.y = fmaf(acc.y, dd, bv.y);
        r.z = fmaf(acc.z, dd, bv.z);
        r.w = fmaf(acc.w, dd, bv.w);
        r.x = r.x > 0.f ? r.x * dd : 0.f;
        r.y = r.y > 0.f ? r.y * dd : 0.f;
        r.z = r.z > 0.f ? r.z * dd : 0.f;
        r.w = r.w > 0.f ? r.w * dd : 0.f;
    } else {
        r.x = acc.x * dd; r.y = acc.y * dd; r.z = acc.z * dd; r.w = acc.w * dd;
    }
    reinterpret_cast<float4*>(out)[(size_t)g * 16 + fo] = r;
}

// Final dual GEMV, register-blocked: 128 rows/block, 8x4/thread.
// Ws[64][64] = [Wmu | Wlg] in LDS; r rows from global into regs.
__global__ __launch_bounds__(256) void k_final2(const float* __restrict__ R,
                                                const float* __restrict__ Wmu,
                                                const float* __restrict__ bmu,
                                                const float* __restrict__ Wlg,
                                                const float* __restrict__ blg,
                                                float* __restrict__ out, int N) {
    __shared__ float Ws[64 * 64];
    int t = threadIdx.x;
    for (int i = t; i < 4096; i += 256) {
        int k = i >> 6, c = i & 63;
        Ws[i] = (c < 32) ? Wmu[(k << 5) + c] : Wlg[(k << 5) + (c - 32)];
    }
    __syncthreads();
    int cg = t & 15, rg = t >> 4;
    int row0 = blockIdx.x * 128 + rg * 8;
    int c4 = cg * 4;
    float4 bv;
    if (c4 < 32) bv = *reinterpret_cast<const float4*>(bmu + c4);
    else         bv = *reinterpret_cast<const float4*>(blg + c4 - 32);
    float4 acc[8];
#pragma unroll
    for (int i = 0; i < 8; ++i) acc[i] = bv;
    for (int k0 = 0; k0 < 64; k0 += 4) {
        float4 xr[8];
#pragma unroll
        for (int i = 0; i < 8; ++i) {
            int rr = row0 + i;
            if (rr >= N) rr = N - 1;
            xr[i] = *reinterpret_cast<const float4*>(R + (size_t)rr * 64 + k0);
        }
#pragma unroll
        for (int kk = 0; kk < 4; ++kk) {
            float4 w = *reinterpret_cast<const float4*>(Ws + (k0 + kk) * 64 + c4);
#pragma unroll
            for (int i = 0; i < 8; ++i) {
                float xv = (&xr[i].x)[kk];
                acc[i].x = fmaf(xv, w.x, acc[i].x);
                acc[i].y = fmaf(xv, w.y, acc[i].y);
                acc[i].z = fmaf(xv, w.z, acc[i].z);
                acc[i].w = fmaf(xv, w.w, acc[i].w);
            }
        }
    }
#pragma unroll
    for (int i = 0; i < 8; ++i) {
        int rr = row0 + i;
        if (rr < N) {
            float* dst = (c4 < 32) ? (out + (size_t)rr * 32 + c4)
                                   : (out + (size_t)N * 32 + (size_t)rr * 32 + (c4 - 32));
            *reinterpret_cast<float4*>(dst) = acc[i];
        }
    }
}

extern "C" void kernel_launch(void* const* d_in, const int* in_sizes, int n_in,
                              void* d_out, int out_size, void* d_ws, size_t ws_size,
                              hipStream_t stream) {
    const float* x   = (const float*)d_in[0];
    const int*   ei  = (const int*)d_in[1];   // [2,E] flat: src then dst
    const float* W1  = (const float*)d_in[2];
    const float* b1  = (const float*)d_in[3];
    const float* Wmu = (const float*)d_in[4];
    const float* bmu = (const float*)d_in[5];
    const float* Wlg = (const float*)d_in[6];
    const float* blg = (const float*)d_in[7];
    float* out = (float*)d_out;

    const int N = in_sizes[0] / 128;
    const int E = in_sizes[1] / 2;

    // workspace: A[N*64] | B[N*64] | ssrc[E] | deg[N] | rowptr[N+1]
    // | dinv[N] | partial[256].   pos[E] ALIASES B (dead before agg<1>).
    float* A       = (float*)d_ws;
    float* B       = A + (size_t)N * 64;
    int*   ssrc    = (int*)(B + (size_t)N * 64);
    int*   deg     = ssrc + E;
    int*   rowptr  = deg + N;
    float* dinv    = (float*)(rowptr + (N + 1));
    int*   partial = (int*)(dinv + N);
    int*   pos     = (int*)B;

    const int NP  = (N + 1023) / 1024;       // scan partials (<=256)
    const int EB  = (E + 1023) / 1024;       // edge blocks (4 edges/thread)
    const int GB  = (N + 127) / 128;         // gemm blocks (128 rows each)
    const int SB  = (N * 16 + 255) / 256;    // scale blocks
    const int AB  = (int)(((size_t)N * 16 + 255) / 256);

    hipMemsetAsync(deg, 0, (size_t)N * sizeof(int), stream);

    // degpos (4-deep atomic pipeline) runs in parallel with the x@W1 GEMM
    k_fused1<<<EB + GB, 256, 0, stream>>>(ei, E, deg, pos, x, W1, A, N, EB);

    k_scan1<<<NP, 256, 0, stream>>>(deg, rowptr, partial, dinv, N);
    k_scan2<<<1, 256, 0, stream>>>(partial, NP, rowptr, N, E);
    k_scan3<<<(N + 255) / 256, 256, 0, stream>>>(rowptr, partial, N);

    // place (atomic-free scatter, 4 edges/thread) || A *= dinv scaling
    k_fused2<<<EB + SB, 256, 0, stream>>>(ei, E, rowptr, pos, ssrc, A, dinv, N, EB);

    // layer 1: B2 = relu(agg(A2)*dd + b1) * dd
    k_agg<1><<<AB, 256, 0, stream>>>(rowptr, ssrc, dinv, A, b1, B, N);
    // layer 2 shared aggregation: A = r = agg(B2)*dd
    k_agg<2><<<AB, 256, 0, stream>>>(rowptr, ssrc, dinv, B, b1, A, N);

    k_final2<<<GB, 256, 0, stream>>>(A, Wmu, bmu, Wlg, blg, out, N);
}

// Round 9
// 348.428 us; speedup vs baseline: 8.7357x; 1.1146x over previous
//
#include <hip/hip_runtime.h>

// ---------------------------------------------------------------------------
// GCN encoder: mu, log = GCNConv(relu(GCNConv(x,W1,b1)), W_mu/W_log)
// Identity: segment_sum((h@W)[src]*norm) == segment_sum(h[src]*norm) @ W
// R1: CSR + gather (killed f32-atomic write-through).
// R2: one atomic pass (degpos), atomic-free place.
// R3: register-blocked GEMMs; degpos||gemm fusion; pre-scaled features.
// R4: XCD-sharded histogram -> FALSIFIED (no delta).
// R5: 4-deep atomic ILP -> FALSIFIED for the atomic pass (no delta).
//     => device atomics are a hard ~18 Gop/s memory-side limit.
// R7: ZERO global atomics. Two-level LDS counting sort builds the CSR:
//     K1 per-block LDS bucket histogram (dst>>6) -> hist[blk][NB] rows
//     K2 column prefix over blocks; K3 bucket-base scan
//     K4 LDS-cursor partition of (src,dst) into bucket order
//     K5 per-bucket (<=64 nodes) LDS count+scan -> rowptr/dinv/ssrc
//     A-prescale pass dropped: agg<1> applies dinv[s] inline (L2-hot).
// R8: resubmit of R7 (container failed twice — no measurement happened).
// ---------------------------------------------------------------------------

#define EPB 8192   // edges per histogram/partition block

// ---- K1: edge blocks -> LDS bucket histogram; gemm blocks -> A = x@W1 ------
__global__ __launch_bounds__(256) void k_fused1(const int* __restrict__ ei, int E,
                                                int* __restrict__ hist, int NB, int shift,
                                                const float* __restrict__ x,
                                                const float* __restrict__ W1,
                                                float* __restrict__ A, int N, int NEB) {
    __shared__ float Ws[8192];   // 32KB: gemm W-tile, aliased as int hist[<=2048]
    int t = threadIdx.x;
    int b = blockIdx.x;
    if (b < NEB) {                       // ---- histogram part ----
        int* h = (int*)Ws;
        for (int k = t; k < NB; k += 256) h[k] = 0;
        __syncthreads();
        int e0 = b * EPB, e1 = min(e0 + EPB, E);
        for (int e = e0 + t * 4; e < e1; e += 1024) {
            if (e + 3 < e1 && ((E & 3) == 0)) {
                int4 d4 = *reinterpret_cast<const int4*>(ei + E + e);
                atomicAdd(&h[d4.x >> shift], 1);
                atomicAdd(&h[d4.y >> shift], 1);
                atomicAdd(&h[d4.z >> shift], 1);
                atomicAdd(&h[d4.w >> shift], 1);
            } else {
                for (int k2 = 0; k2 < 4; ++k2) {
                    int e2 = e + k2;
                    if (e2 < e1) atomicAdd(&h[ei[E + e2] >> shift], 1);
                }
            }
        }
        __syncthreads();
        for (int k = t; k < NB; k += 256) hist[(size_t)b * NB + k] = h[k];
        return;
    }
    // ---- gemm part: 128 rows/block, thread = 8 rows x 4 cols ----
    int bb = b - NEB;
    for (int i = t; i < 2048; i += 256)
        reinterpret_cast<float4*>(Ws)[i] = reinterpret_cast<const float4*>(W1)[i];
    __syncthreads();
    int cg = t & 15, rg = t >> 4;
    int row0 = bb * 128 + rg * 8;
    int c4 = cg * 4;
    float4 acc[8];
#pragma unroll
    for (int i = 0; i < 8; ++i) acc[i] = {0.f, 0.f, 0.f, 0.f};
    for (int k0 = 0; k0 < 128; k0 += 4) {
        float4 xr[8];
#pragma unroll
        for (int i = 0; i < 8; ++i) {
            int rr = row0 + i;
            if (rr >= N) rr = N - 1;
            xr[i] = *reinterpret_cast<const float4*>(x + (size_t)rr * 128 + k0);
        }
#pragma unroll
        for (int kk = 0; kk < 4; ++kk) {
            float4 w = *reinterpret_cast<const float4*>(Ws + (k0 + kk) * 64 + c4);
#pragma unroll
            for (int i = 0; i < 8; ++i) {
                float xv = (&xr[i].x)[kk];
                acc[i].x = fmaf(xv, w.x, acc[i].x);
                acc[i].y = fmaf(xv, w.y, acc[i].y);
                acc[i].z = fmaf(xv, w.z, acc[i].z);
                acc[i].w = fmaf(xv, w.w, acc[i].w);
            }
        }
    }
#pragma unroll
    for (int i = 0; i < 8; ++i) {
        int rr = row0 + i;
        if (rr < N) *reinterpret_cast<float4*>(A + (size_t)rr * 64 + c4) = acc[i];
    }
}

// ---- K2: in-place column-exclusive prefix over blocks; colTotal out --------
__global__ void k_colpre(int* __restrict__ hist, int* __restrict__ colTotal,
                         int NB, int NBLK) {
    int k = blockIdx.x * 256 + threadIdx.x;
    if (k >= NB) return;
    int run = 0;
#pragma unroll 4
    for (int b = 0; b < NBLK; ++b) {
        int* p = hist + (size_t)b * NB + k;
        int v = *p;
        *p = run;
        run += v;
    }
    colTotal[k] = run;
}

// ---- K3: exclusive scan of colTotal[NB<=2048] -> bucketStart[NB+1] ---------
__global__ __launch_bounds__(256) void k_bscan(const int* __restrict__ colTotal,
                                               int* __restrict__ bucketStart,
                                               int NB, int E,
                                               int* __restrict__ rowptr, int N) {
    __shared__ int sdata[256];
    int t = threadIdx.x;
    int v[8];
    int sum = 0;
#pragma unroll
    for (int i = 0; i < 8; ++i) {
        int k = t * 8 + i;
        v[i] = (k < NB) ? colTotal[k] : 0;
        sum += v[i];
    }
    sdata[t] = sum;
    __syncthreads();
    for (int off = 1; off < 256; off <<= 1) {
        int val = (t >= off) ? sdata[t - off] : 0;
        __syncthreads();
        sdata[t] += val;
        __syncthreads();
    }
    int excl = (t > 0) ? sdata[t - 1] : 0;
#pragma unroll
    for (int i = 0; i < 8; ++i) {
        int k = t * 8 + i;
        if (k < NB) bucketStart[k] = excl;
        excl += v[i];
    }
    if (t == 0) { bucketStart[NB] = E; rowptr[N] = E; }
}

// ---- K4: LDS-cursor partition of (src,dst) into bucket-major order ---------
__global__ __launch_bounds__(256) void k_part(const int* __restrict__ ei, int E,
                                              const int* __restrict__ hist,
                                              const int* __restrict__ bucketStart,
                                              int NB, int shift,
                                              int2* __restrict__ part) {
    __shared__ int cur[2048];
    int t = threadIdx.x, b = blockIdx.x;
    for (int k = t; k < NB; k += 256)
        cur[k] = hist[(size_t)b * NB + k] + bucketStart[k];
    __syncthreads();
    int e0 = b * EPB, e1 = min(e0 + EPB, E);
    for (int e = e0 + t * 4; e < e1; e += 1024) {
        if (e + 3 < e1 && ((E & 3) == 0)) {
            int4 s4 = *reinterpret_cast<const int4*>(ei + e);
            int4 d4 = *reinterpret_cast<const int4*>(ei + E + e);
            int p;
            p = atomicAdd(&cur[d4.x >> shift], 1); part[p] = make_int2(s4.x, d4.x);
            p = atomicAdd(&cur[d4.y >> shift], 1); part[p] = make_int2(s4.y, d4.y);
            p = atomicAdd(&cur[d4.z >> shift], 1); part[p] = make_int2(s4.z, d4.z);
            p = atomicAdd(&cur[d4.w >> shift], 1); part[p] = make_int2(s4.w, d4.w);
        } else {
            for (int k2 = 0; k2 < 4; ++k2) {
                int e2 = e + k2;
                if (e2 < e1) {
                    int s = ei[e2], d = ei[E + e2];
                    int p = atomicAdd(&cur[d >> shift], 1);
                    part[p] = make_int2(s, d);
                }
            }
        }
    }
}

// ---- K5: per-bucket CSR finalize: rowptr, dinv, ssrc -----------------------
__global__ __launch_bounds__(256) void k_bucket(const int2* __restrict__ part,
                                                const int* __restrict__ bucketStart,
                                                int NB, int shift,
                                                int* __restrict__ ssrc,
                                                int* __restrict__ rowptr,
                                                float* __restrict__ dinv, int N) {
    __shared__ int cnt[2048];
    __shared__ int base[2048];
    int t = threadIdx.x, b = blockIdx.x;
    int lo = bucketStart[b], hi = bucketStart[b + 1];
    int n0 = b << shift;
    int nn = min(1 << shift, N - n0);
    for (int i = t; i < nn; i += 256) cnt[i] = 0;
    __syncthreads();
    for (int e = lo + t; e < hi; e += 256) {
        int2 pd = part[e];
        atomicAdd(&cnt[pd.y - n0], 1);
    }
    __syncthreads();
    if (t == 0) {
        int run = 0;
        for (int i = 0; i < nn; ++i) { base[i] = run; run += cnt[i]; }
    }
    __syncthreads();
    for (int i = t; i < nn; i += 256) {
        rowptr[n0 + i] = lo + base[i];
        dinv[n0 + i] = rsqrtf((float)(cnt[i] + 1));
    }
    __syncthreads();
    for (int e = lo + t; e < hi; e += 256) {
        int2 pd = part[e];
        int p = atomicAdd(&base[pd.y - n0], 1);
        ssrc[lo + p] = pd.x;
    }
}

// ---- CSR gather-aggregate, unrolled x4 (4 outstanding 64B gathers) ---------
// EPI==1: feat = raw A; inner applies dinv[s]; out = relu((acc)*dd + b1) * dd
// EPI==2: feat = pre-scaled B2; inner pure add;  out = (acc)*dd  (= r)
template <int EPI>
__global__ __launch_bounds__(256) void k_agg(const int* __restrict__ rowptr,
                                             const int* __restrict__ ssrc,
                                             const float* __restrict__ dinv,
                                             const float* __restrict__ feat,
                                             const float* __restrict__ bias,
                                             float* __restrict__ out, int N) {
    int idx = blockIdx.x * 256 + threadIdx.x;
    int g = idx >> 4;
    if (g >= N) return;
    int fo = idx & 15;                           // float4 offset within row
    const float4* F = reinterpret_cast<const float4*>(feat);
    int beg = rowptr[g], end = rowptr[g + 1];
    float dd = dinv[g];
    float4 self = F[(size_t)g * 16 + fo];
    float4 a0, a1 = {0,0,0,0}, a2 = {0,0,0,0}, a3 = {0,0,0,0};
    if (EPI == 1) { a0.x = self.x * dd; a0.y = self.y * dd; a0.z = self.z * dd; a0.w = self.w * dd; }
    else a0 = self;
    int j = beg;
    for (; j + 4 <= end; j += 4) {
        int s0 = ssrc[j], s1 = ssrc[j + 1], s2 = ssrc[j + 2], s3 = ssrc[j + 3];
        float4 v0 = F[(size_t)s0 * 16 + fo];
        float4 v1 = F[(size_t)s1 * 16 + fo];
        float4 v2 = F[(size_t)s2 * 16 + fo];
        float4 v3 = F[(size_t)s3 * 16 + fo];
        if (EPI == 1) {
            float n0 = dinv[s0], n1 = dinv[s1], n2 = dinv[s2], n3 = dinv[s3];
            a0.x = fmaf(v0.x, n0, a0.x); a0.y = fmaf(v0.y, n0, a0.y);
            a0.z = fmaf(v0.z, n0, a0.z); a0.w = fmaf(v0.w, n0, a0.w);
            a1.x = fmaf(v1.x, n1, a1.x); a1.y = fmaf(v1.y, n1, a1.y);
            a1.z = fmaf(v1.z, n1, a1.z); a1.w = fmaf(v1.w, n1, a1.w);
            a2.x = fmaf(v2.x, n2, a2.x); a2.y = fmaf(v2.y, n2, a2.y);
            a2.z = fmaf(v2.z, n2, a2.z); a2.w = fmaf(v2.w, n2, a2.w);
            a3.x = fmaf(v3.x, n3, a3.x); a3.y = fmaf(v3.y, n3, a3.y);
            a3.z = fmaf(v3.z, n3, a3.z); a3.w = fmaf(v3.w, n3, a3.w);
        } else {
            a0.x += v0.x; a0.y += v0.y; a0.z += v0.z; a0.w += v0.w;
            a1.x += v1.x; a1.y += v1.y; a1.z += v1.z; a1.w += v1.w;
            a2.x += v2.x; a2.y += v2.y; a2.z += v2.z; a2.w += v2.w;
            a3.x += v3.x; a3.y += v3.y; a3.z += v3.z; a3.w += v3.w;
        }
    }
    for (; j < end; ++j) {
        int s = ssrc[j];
        float4 v = F[(size_t)s * 16 + fo];
        if (EPI == 1) {
            float ns = dinv[s];
            a1.x = fmaf(v.x, ns, a1.x); a1.y = fmaf(v.y, ns, a1.y);
            a1.z = fmaf(v.z, ns, a1.z); a1.w = fmaf(v.w, ns, a1.w);
        } else {
            a1.x += v.x; a1.y += v.y; a1.z += v.z; a1.w += v.w;
        }
    }
    float4 acc;
    acc.x = (a0.x + a1.x) + (a2.x + a3.x);
    acc.y = (a0.y + a1.y) + (a2.y + a3.y);
    acc.z = (a0.z + a1.z) + (a2.z + a3.z);
    acc.w = (a0.w + a1.w) + (a2.w + a3.w);
    float4 r;
    if (EPI == 1) {
        const float4 bv = *reinterpret_cast<const float4*>(bias + (fo << 2));
        r.x = fmaf(acc.x, dd, bv.x);
        r.y = fmaf(acc.y, dd, bv.y);
        r.z = fmaf(acc.z, dd, bv.z);
        r.w = fmaf(acc.w, dd, bv.w);
        r.x = r.x > 0.f ? r.x * dd : 0.f;
        r.y = r.y > 0.f ? r.y * dd : 0.f;
        r.z = r.z > 0.f ? r.z * dd : 0.f;
        r.w = r.w > 0.f ? r.w * dd : 0.f;
    } else {
        r.x = acc.x * dd; r.y = acc.y * dd; r.z = acc.z * dd; r.w = acc.w * dd;
    }
    reinterpret_cast<float4*>(out)[(size_t)g * 16 + fo] = r;
}

// ---- Final dual GEMV, register-blocked: 128 rows/block, 8x4/thread ---------
__global__ __launch_bounds__(256) void k_final2(const float* __restrict__ R,
                                                const float* __restrict__ Wmu,
                                                const float* __restrict__ bmu,
                                                const float* __restrict__ Wlg,
                                                const float* __restrict__ blg,
                                                float* __restrict__ out, int N) {
    __shared__ float Ws[64 * 64];
    int t = threadIdx.x;
    for (int i = t; i < 4096; i += 256) {
        int k = i >> 6, c = i & 63;
        Ws[i] = (c < 32) ? Wmu[(k << 5) + c] : Wlg[(k << 5) + (c - 32)];
    }
    __syncthreads();
    int cg = t & 15, rg = t >> 4;
    int row0 = blockIdx.x * 128 + rg * 8;
    int c4 = cg * 4;
    float4 bv;
    if (c4 < 32) bv = *reinterpret_cast<const float4*>(bmu + c4);
    else         bv = *reinterpret_cast<const float4*>(blg + c4 - 32);
    float4 acc[8];
#pragma unroll
    for (int i = 0; i < 8; ++i) acc[i] = bv;
    for (int k0 = 0; k0 < 64; k0 += 4) {
        float4 xr[8];
#pragma unroll
        for (int i = 0; i < 8; ++i) {
            int rr = row0 + i;
            if (rr >= N) rr = N - 1;
            xr[i] = *reinterpret_cast<const float4*>(R + (size_t)rr * 64 + k0);
        }
#pragma unroll
        for (int kk = 0; kk < 4; ++kk) {
            float4 w = *reinterpret_cast<const float4*>(Ws + (k0 + kk) * 64 + c4);
#pragma unroll
            for (int i = 0; i < 8; ++i) {
                float xv = (&xr[i].x)[kk];
                acc[i].x = fmaf(xv, w.x, acc[i].x);
                acc[i].y = fmaf(xv, w.y, acc[i].y);
                acc[i].z = fmaf(xv, w.z, acc[i].z);
                acc[i].w = fmaf(xv, w.w, acc[i].w);
            }
        }
    }
#pragma unroll
    for (int i = 0; i < 8; ++i) {
        int rr = row0 + i;
        if (rr < N) {
            float* dst = (c4 < 32) ? (out + (size_t)rr * 32 + c4)
                                   : (out + (size_t)N * 32 + (size_t)rr * 32 + (c4 - 32));
            *reinterpret_cast<float4*>(dst) = acc[i];
        }
    }
}

extern "C" void kernel_launch(void* const* d_in, const int* in_sizes, int n_in,
                              void* d_out, int out_size, void* d_ws, size_t ws_size,
                              hipStream_t stream) {
    const float* x   = (const float*)d_in[0];
    const int*   ei  = (const int*)d_in[1];   // [2,E] flat: src then dst
    const float* W1  = (const float*)d_in[2];
    const float* b1  = (const float*)d_in[3];
    const float* Wmu = (const float*)d_in[4];
    const float* bmu = (const float*)d_in[5];
    const float* Wlg = (const float*)d_in[6];
    const float* blg = (const float*)d_in[7];
    float* out = (float*)d_out;

    const int N = in_sizes[0] / 128;
    const int E = in_sizes[1] / 2;

    int shift = 6;
    while ((((N + (1 << shift) - 1) >> shift)) > 2048) ++shift;
    const int NB  = (N + (1 << shift) - 1) >> shift;   // buckets (<=2048)
    const int NEB = (E + EPB - 1) / EPB;               // edge blocks
    const int GB  = (N + 127) / 128;                   // gemm blocks
    const int AB  = (int)(((size_t)N * 16 + 255) / 256);

    // workspace: A[N*64] | B[N*64] | ssrc[E] | rowptr[N+1] | dinv[N]
    // Aliased inside B (all dead before k_agg<1> writes B):
    //   part[E] int2 | hist[NEB*NB] | colTotal[NB] | bucketStart[NB+1]
    float* A      = (float*)d_ws;
    float* B      = A + (size_t)N * 64;
    int*   ssrc   = (int*)(B + (size_t)N * 64);
    int*   rowptr = ssrc + E;
    float* dinv   = (float*)(rowptr + (N + 1));

    int2* part        = (int2*)B;
    int*  hist        = (int*)B + (size_t)2 * E;
    int*  colTotal    = hist + (size_t)NEB * NB;
    int*  bucketStart = colTotal + NB;

    // K1: per-block LDS bucket histograms || x@W1 GEMM
    k_fused1<<<NEB + GB, 256, 0, stream>>>(ei, E, hist, NB, shift, x, W1, A, N, NEB);
    // K2: column-exclusive prefix over blocks (in place) + colTotal
    k_colpre<<<(NB + 255) / 256, 256, 0, stream>>>(hist, colTotal, NB, NEB);
    // K3: bucket-base scan
    k_bscan<<<1, 256, 0, stream>>>(colTotal, bucketStart, NB, E, rowptr, N);
    // K4: partition (src,dst) into bucket-major order via LDS cursors
    k_part<<<NEB, 256, 0, stream>>>(ei, E, hist, bucketStart, NB, shift, part);
    // K5: per-bucket CSR finalize (rowptr, dinv, ssrc)
    k_bucket<<<NB, 256, 0, stream>>>(part, bucketStart, NB, shift, ssrc, rowptr, dinv, N);

    // layer 1: B2 = relu(agg(dinv[s]*A[s])*dd + b1) * dd
    k_agg<1><<<AB, 256, 0, stream>>>(rowptr, ssrc, dinv, A, b1, B, N);
    // layer 2 shared aggregation: A = r = agg(B2)*dd
    k_agg<2><<<AB, 256, 0, stream>>>(rowptr, ssrc, dinv, B, b1, A, N);

    k_final2<<<GB, 256, 0, stream>>>(A, Wmu, bmu, Wlg, blg, out, N);
}

// Round 10
// 295.824 us; speedup vs baseline: 10.2891x; 1.1778x over previous
//
#include <hip/hip_runtime.h>
#include <hip/hip_fp16.h>

// ---------------------------------------------------------------------------
// GCN encoder: mu, log = GCNConv(relu(GCNConv(x,W1,b1)), W_mu/W_log)
// Identity: segment_sum((h@W)[src]*norm) == segment_sum(h[src]*norm) @ W
// R1: CSR + gather (killed f32-atomic write-through).
// R2-R5: one atomic pass; reg-blocked GEMMs; sharding/ILP on atomics FALSIFIED
//        => device atomics are a hard ~18 Gop/s memory-side limit.
// R7: ZERO global atomics — two-level LDS counting sort builds the CSR.
// R9: fp16 feature buffers (A, B2, r): gather payload 256B -> 128B per edge.
//     agg was bytes-bound (FETCH 194MB, 3.67TB/s, VALU 15%) -> halve bytes.
//     Accumulation stays f32; fp16 (not bf16) keeps absmax ~4e-3 << 1.2e-2.
// ---------------------------------------------------------------------------

#define EPB 8192   // edges per histogram/partition block

__device__ inline uint2 f4_to_h4(float4 v) {
    __half2 lo = __floats2half2_rn(v.x, v.y);
    __half2 hi = __floats2half2_rn(v.z, v.w);
    uint2 u;
    u.x = *reinterpret_cast<unsigned int*>(&lo);
    u.y = *reinterpret_cast<unsigned int*>(&hi);
    return u;
}
__device__ inline float4 h4_to_f4(uint2 u) {
    __half2 lo = *reinterpret_cast<__half2*>(&u.x);
    __half2 hi = *reinterpret_cast<__half2*>(&u.y);
    float2 a = __half22float2(lo);
    float2 b = __half22float2(hi);
    return make_float4(a.x, a.y, b.x, b.y);
}

// ---- K1: edge blocks -> LDS bucket histogram; gemm blocks -> A = x@W1 (fp16)
__global__ __launch_bounds__(256) void k_fused1(const int* __restrict__ ei, int E,
                                                int* __restrict__ hist, int NB, int shift,
                                                const float* __restrict__ x,
                                                const float* __restrict__ W1,
                                                __half* __restrict__ A, int N, int NEB) {
    __shared__ float Ws[8192];   // 32KB: gemm W-tile, aliased as int hist[<=2048]
    int t = threadIdx.x;
    int b = blockIdx.x;
    if (b < NEB) {                       // ---- histogram part ----
        int* h = (int*)Ws;
        for (int k = t; k < NB; k += 256) h[k] = 0;
        __syncthreads();
        int e0 = b * EPB, e1 = min(e0 + EPB, E);
        for (int e = e0 + t * 4; e < e1; e += 1024) {
            if (e + 3 < e1 && ((E & 3) == 0)) {
                int4 d4 = *reinterpret_cast<const int4*>(ei + E + e);
                atomicAdd(&h[d4.x >> shift], 1);
                atomicAdd(&h[d4.y >> shift], 1);
                atomicAdd(&h[d4.z >> shift], 1);
                atomicAdd(&h[d4.w >> shift], 1);
            } else {
                for (int k2 = 0; k2 < 4; ++k2) {
                    int e2 = e + k2;
                    if (e2 < e1) atomicAdd(&h[ei[E + e2] >> shift], 1);
                }
            }
        }
        __syncthreads();
        for (int k = t; k < NB; k += 256) hist[(size_t)b * NB + k] = h[k];
        return;
    }
    // ---- gemm part: 128 rows/block, thread = 8 rows x 4 cols ----
    int bb = b - NEB;
    for (int i = t; i < 2048; i += 256)
        reinterpret_cast<float4*>(Ws)[i] = reinterpret_cast<const float4*>(W1)[i];
    __syncthreads();
    int cg = t & 15, rg = t >> 4;
    int row0 = bb * 128 + rg * 8;
    int c4 = cg * 4;
    float4 acc[8];
#pragma unroll
    for (int i = 0; i < 8; ++i) acc[i] = {0.f, 0.f, 0.f, 0.f};
    for (int k0 = 0; k0 < 128; k0 += 4) {
        float4 xr[8];
#pragma unroll
        for (int i = 0; i < 8; ++i) {
            int rr = row0 + i;
            if (rr >= N) rr = N - 1;
            xr[i] = *reinterpret_cast<const float4*>(x + (size_t)rr * 128 + k0);
        }
#pragma unroll
        for (int kk = 0; kk < 4; ++kk) {
            float4 w = *reinterpret_cast<const float4*>(Ws + (k0 + kk) * 64 + c4);
#pragma unroll
            for (int i = 0; i < 8; ++i) {
                float xv = (&xr[i].x)[kk];
                acc[i].x = fmaf(xv, w.x, acc[i].x);
                acc[i].y = fmaf(xv, w.y, acc[i].y);
                acc[i].z = fmaf(xv, w.z, acc[i].z);
                acc[i].w = fmaf(xv, w.w, acc[i].w);
            }
        }
    }
#pragma unroll
    for (int i = 0; i < 8; ++i) {
        int rr = row0 + i;
        if (rr < N)
            *reinterpret_cast<uint2*>(A + (size_t)rr * 64 + c4) = f4_to_h4(acc[i]);
    }
}

// ---- K2: in-place column-exclusive prefix over blocks; colTotal out --------
__global__ void k_colpre(int* __restrict__ hist, int* __restrict__ colTotal,
                         int NB, int NBLK) {
    int k = blockIdx.x * 256 + threadIdx.x;
    if (k >= NB) return;
    int run = 0;
#pragma unroll 4
    for (int b = 0; b < NBLK; ++b) {
        int* p = hist + (size_t)b * NB + k;
        int v = *p;
        *p = run;
        run += v;
    }
    colTotal[k] = run;
}

// ---- K3: exclusive scan of colTotal[NB<=2048] -> bucketStart[NB+1] ---------
__global__ __launch_bounds__(256) void k_bscan(const int* __restrict__ colTotal,
                                               int* __restrict__ bucketStart,
                                               int NB, int E,
                                               int* __restrict__ rowptr, int N) {
    __shared__ int sdata[256];
    int t = threadIdx.x;
    int v[8];
    int sum = 0;
#pragma unroll
    for (int i = 0; i < 8; ++i) {
        int k = t * 8 + i;
        v[i] = (k < NB) ? colTotal[k] : 0;
        sum += v[i];
    }
    sdata[t] = sum;
    __syncthreads();
    for (int off = 1; off < 256; off <<= 1) {
        int val = (t >= off) ? sdata[t - off] : 0;
        __syncthreads();
        sdata[t] += val;
        __syncthreads();
    }
    int excl = (t > 0) ? sdata[t - 1] : 0;
#pragma unroll
    for (int i = 0; i < 8; ++i) {
        int k = t * 8 + i;
        if (k < NB) bucketStart[k] = excl;
        excl += v[i];
    }
    if (t == 0) { bucketStart[NB] = E; rowptr[N] = E; }
}

// ---- K4: LDS-cursor partition of (src,dst) into bucket-major order ---------
__global__ __launch_bounds__(256) void k_part(const int* __restrict__ ei, int E,
                                              const int* __restrict__ hist,
                                              const int* __restrict__ bucketStart,
                                              int NB, int shift,
                                              int2* __restrict__ part) {
    __shared__ int cur[2048];
    int t = threadIdx.x, b = blockIdx.x;
    for (int k = t; k < NB; k += 256)
        cur[k] = hist[(size_t)b * NB + k] + bucketStart[k];
    __syncthreads();
    int e0 = b * EPB, e1 = min(e0 + EPB, E);
    for (int e = e0 + t * 4; e < e1; e += 1024) {
        if (e + 3 < e1 && ((E & 3) == 0)) {
            int4 s4 = *reinterpret_cast<const int4*>(ei + e);
            int4 d4 = *reinterpret_cast<const int4*>(ei + E + e);
            int p;
            p = atomicAdd(&cur[d4.x >> shift], 1); part[p] = make_int2(s4.x, d4.x);
            p = atomicAdd(&cur[d4.y >> shift], 1); part[p] = make_int2(s4.y, d4.y);
            p = atomicAdd(&cur[d4.z >> shift], 1); part[p] = make_int2(s4.z, d4.z);
            p = atomicAdd(&cur[d4.w >> shift], 1); part[p] = make_int2(s4.w, d4.w);
        } else {
            for (int k2 = 0; k2 < 4; ++k2) {
                int e2 = e + k2;
                if (e2 < e1) {
                    int s = ei[e2], d = ei[E + e2];
                    int p = atomicAdd(&cur[d >> shift], 1);
                    part[p] = make_int2(s, d);
                }
            }
        }
    }
}

// ---- K5: per-bucket CSR finalize: rowptr, dinv, ssrc -----------------------
__global__ __launch_bounds__(256) void k_bucket(const int2* __restrict__ part,
                                                const int* __restrict__ bucketStart,
                                                int NB, int shift,
                                                int* __restrict__ ssrc,
                                                int* __restrict__ rowptr,
                                                float* __restrict__ dinv, int N) {
    __shared__ int cnt[2048];
    __shared__ int base[2048];
    int t = threadIdx.x, b = blockIdx.x;
    int lo = bucketStart[b], hi = bucketStart[b + 1];
    int n0 = b << shift;
    int nn = min(1 << shift, N - n0);
    for (int i = t; i < nn; i += 256) cnt[i] = 0;
    __syncthreads();
    for (int e = lo + t; e < hi; e += 256) {
        int2 pd = part[e];
        atomicAdd(&cnt[pd.y - n0], 1);
    }
    __syncthreads();
    if (t == 0) {
        int run = 0;
        for (int i = 0; i < nn; ++i) { base[i] = run; run += cnt[i]; }
    }
    __syncthreads();
    for (int i = t; i < nn; i += 256) {
        rowptr[n0 + i] = lo + base[i];
        dinv[n0 + i] = rsqrtf((float)(cnt[i] + 1));
    }
    __syncthreads();
    for (int e = lo + t; e < hi; e += 256) {
        int2 pd = part[e];
        int p = atomicAdd(&base[pd.y - n0], 1);
        ssrc[lo + p] = pd.x;
    }
}

// ---- CSR gather-aggregate over fp16 rows (128B/edge), unrolled x4 ----------
// EPI==1: feat = A(h);  inner applies dinv[s]; out = fp16( relu((acc)*dd+b1)*dd )
// EPI==2: feat = B2(h); inner pure add;        out = fp16( (acc)*dd )   (= r)
template <int EPI>
__global__ __launch_bounds__(256) void k_agg(const int* __restrict__ rowptr,
                                             const int* __restrict__ ssrc,
                                             const float* __restrict__ dinv,
                                             const __half* __restrict__ feat,
                                             const float* __restrict__ bias,
                                             __half* __restrict__ out, int N) {
    int idx = blockIdx.x * 256 + threadIdx.x;
    int g = idx >> 4;
    if (g >= N) return;
    int fo = idx & 15;                           // uint2 (4-half) offset in row
    const uint2* F = reinterpret_cast<const uint2*>(feat);
    int beg = rowptr[g], end = rowptr[g + 1];
    float dd = dinv[g];
    float4 self = h4_to_f4(F[(size_t)g * 16 + fo]);
    float4 a0, a1 = {0,0,0,0}, a2 = {0,0,0,0}, a3 = {0,0,0,0};
    if (EPI == 1) { a0.x = self.x * dd; a0.y = self.y * dd; a0.z = self.z * dd; a0.w = self.w * dd; }
    else a0 = self;
    int j = beg;
    for (; j + 4 <= end; j += 4) {
        int s0 = ssrc[j], s1 = ssrc[j + 1], s2 = ssrc[j + 2], s3 = ssrc[j + 3];
        float4 v0 = h4_to_f4(F[(size_t)s0 * 16 + fo]);
        float4 v1 = h4_to_f4(F[(size_t)s1 * 16 + fo]);
        float4 v2 = h4_to_f4(F[(size_t)s2 * 16 + fo]);
        float4 v3 = h4_to_f4(F[(size_t)s3 * 16 + fo]);
        if (EPI == 1) {
            float n0 = dinv[s0], n1 = dinv[s1], n2 = dinv[s2], n3 = dinv[s3];
            a0.x = fmaf(v0.x, n0, a0.x); a0.y = fmaf(v0.y, n0, a0.y);
            a0.z = fmaf(v0.z, n0, a0.z); a0.w = fmaf(v0.w, n0, a0.w);
            a1.x = fmaf(v1.x, n1, a1.x); a1.y = fmaf(v1.y, n1, a1.y);
            a1.z = fmaf(v1.z, n1, a1.z); a1.w = fmaf(v1.w, n1, a1.w);
            a2.x = fmaf(v2.x, n2, a2.x); a2.y = fmaf(v2.y, n2, a2.y);
            a2.z = fmaf(v2.z, n2, a2.z); a2.w = fmaf(v2.w, n2, a2.w);
            a3.x = fmaf(v3.x, n3, a3.x); a3.y = fmaf(v3.y, n3, a3.y);
            a3.z = fmaf(v3.z, n3, a3.z); a3.w = fmaf(v3.w, n3, a3.w);
        } else {
            a0.x += v0.x; a0.y += v0.y; a0.z += v0.z; a0.w += v0.w;
            a1.x += v1.x; a1.y += v1.y; a1.z += v1.z; a1.w += v1.w;
            a2.x += v2.x; a2.y += v2.y; a2.z += v2.z; a2.w += v2.w;
            a3.x += v3.x; a3.y += v3.y; a3.z += v3.z; a3.w += v3.w;
        }
    }
    for (; j < end; ++j) {
        int s = ssrc[j];
        float4 v = h4_to_f4(F[(size_t)s * 16 + fo]);
        if (EPI == 1) {
            float ns = dinv[s];
            a1.x = fmaf(v.x, ns, a1.x); a1.y = fmaf(v.y, ns, a1.y);
            a1.z = fmaf(v.z, ns, a1.z); a1.w = fmaf(v.w, ns, a1.w);
        } else {
            a1.x += v.x; a1.y += v.y; a1.z += v.z; a1.w += v.w;
        }
    }
    float4 acc;
    acc.x = (a0.x + a1.x) + (a2.x + a3.x);
    acc.y = (a0.y + a1.y) + (a2.y + a3.y);
    acc.z = (a0.z + a1.z) + (a2.z + a3.z);
    acc.w = (a0.w + a1.w) + (a2.w + a3.w);
    float4 r;
    if (EPI == 1) {
        const float4 bv = *reinterpret_cast<const float4*>(bias + (fo << 2));
        r.x = fmaf(acc.x, dd, bv.x);
        r.y = fmaf(acc.y, dd, bv.y);
        r.z = fmaf(acc.z, dd, bv.z);
        r.w = fmaf(acc.w, dd, bv.w);
        r.x = r.x > 0.f ? r.x * dd : 0.f;
        r.y = r.y > 0.f ? r.y * dd : 0.f;
        r.z = r.z > 0.f ? r.z * dd : 0.f;
        r.w = r.w > 0.f ? r.w * dd : 0.f;
    } else {
        r.x = acc.x * dd; r.y = acc.y * dd; r.z = acc.z * dd; r.w = acc.w * dd;
    }
    reinterpret_cast<uint2*>(out)[(size_t)g * 16 + fo] = f4_to_h4(r);
}

// ---- Final dual GEMV (fp16 R): 128 rows/block, 8x4/thread ------------------
__global__ __launch_bounds__(256) void k_final2(const __half* __restrict__ R,
                                                const float* __restrict__ Wmu,
                                                const float* __restrict__ bmu,
                                                const float* __restrict__ Wlg,
                                                const float* __restrict__ blg,
                                                float* __restrict__ out, int N) {
    __shared__ float Ws[64 * 64];
    int t = threadIdx.x;
    for (int i = t; i < 4096; i += 256) {
        int k = i >> 6, c = i & 63;
        Ws[i] = (c < 32) ? Wmu[(k << 5) + c] : Wlg[(k << 5) + (c - 32)];
    }
    __syncthreads();
    int cg = t & 15, rg = t >> 4;
    int row0 = blockIdx.x * 128 + rg * 8;
    int c4 = cg * 4;
    float4 bv;
    if (c4 < 32) bv = *reinterpret_cast<const float4*>(bmu + c4);
    else         bv = *reinterpret_cast<const float4*>(blg + c4 - 32);
    float4 acc[8];
#pragma unroll
    for (int i = 0; i < 8; ++i) acc[i] = bv;
    const uint2* R2 = reinterpret_cast<const uint2*>(R);
    for (int k0 = 0; k0 < 64; k0 += 4) {
        float4 xr[8];
#pragma unroll
        for (int i = 0; i < 8; ++i) {
            int rr = row0 + i;
            if (rr >= N) rr = N - 1;
            xr[i] = h4_to_f4(R2[(size_t)rr * 16 + (k0 >> 2)]);
        }
#pragma unroll
        for (int kk = 0; kk < 4; ++kk) {
            float4 w = *reinterpret_cast<const float4*>(Ws + (k0 + kk) * 64 + c4);
#pragma unroll
            for (int i = 0; i < 8; ++i) {
                float xv = (&xr[i].x)[kk];
                acc[i].x = fmaf(xv, w.x, acc[i].x);
                acc[i].y = fmaf(xv, w.y, acc[i].y);
                acc[i].z = fmaf(xv, w.z, acc[i].z);
                acc[i].w = fmaf(xv, w.w, acc[i].w);
            }
        }
    }
#pragma unroll
    for (int i = 0; i < 8; ++i) {
        int rr = row0 + i;
        if (rr < N) {
            float* dst = (c4 < 32) ? (out + (size_t)rr * 32 + c4)
                                   : (out + (size_t)N * 32 + (size_t)rr * 32 + (c4 - 32));
            *reinterpret_cast<float4*>(dst) = acc[i];
        }
    }
}

extern "C" void kernel_launch(void* const* d_in, const int* in_sizes, int n_in,
                              void* d_out, int out_size, void* d_ws, size_t ws_size,
                              hipStream_t stream) {
    const float* x   = (const float*)d_in[0];
    const int*   ei  = (const int*)d_in[1];   // [2,E] flat: src then dst
    const float* W1  = (const float*)d_in[2];
    const float* b1  = (const float*)d_in[3];
    const float* Wmu = (const float*)d_in[4];
    const float* bmu = (const float*)d_in[5];
    const float* Wlg = (const float*)d_in[6];
    const float* blg = (const float*)d_in[7];
    float* out = (float*)d_out;

    const int N = in_sizes[0] / 128;
    const int E = in_sizes[1] / 2;

    int shift = 6;
    while ((((N + (1 << shift) - 1) >> shift)) > 2048) ++shift;
    const int NB  = (N + (1 << shift) - 1) >> shift;   // buckets (<=2048)
    const int NEB = (E + EPB - 1) / EPB;               // edge blocks
    const int GB  = (N + 127) / 128;                   // gemm blocks
    const int AB  = (int)(((size_t)N * 16 + 255) / 256);

    // workspace (linear, ~47MB):
    // Ah[N*64]h | Bh[N*64]h | ssrc[E] | rowptr[N+1] | dinv[N] | part[E]int2
    // | hist[NEB*NB] | colTotal[NB] | bucketStart[NB+1]
    // r (fp16, agg<2> out) ALIASES Ah — A is dead after agg<1>.
    __half* Ah        = (__half*)d_ws;
    __half* Bh        = Ah + (size_t)N * 64;
    int*    ssrc      = (int*)(Bh + (size_t)N * 64);
    int*    rowptr    = ssrc + E;
    float*  dinv      = (float*)(rowptr + (N + 1));
    int2*   part      = (int2*)(dinv + N);
    int*    hist      = (int*)(part + E);
    int*    colTotal  = hist + (size_t)NEB * NB;
    int*    bucketStart = colTotal + NB;

    // K1: per-block LDS bucket histograms || x@W1 GEMM (fp16 A out)
    k_fused1<<<NEB + GB, 256, 0, stream>>>(ei, E, hist, NB, shift, x, W1, Ah, N, NEB);
    // K2: column-exclusive prefix over blocks (in place) + colTotal
    k_colpre<<<(NB + 255) / 256, 256, 0, stream>>>(hist, colTotal, NB, NEB);
    // K3: bucket-base scan
    k_bscan<<<1, 256, 0, stream>>>(colTotal, bucketStart, NB, E, rowptr, N);
    // K4: partition (src,dst) into bucket-major order via LDS cursors
    k_part<<<NEB, 256, 0, stream>>>(ei, E, hist, bucketStart, NB, shift, part);
    // K5: per-bucket CSR finalize (rowptr, dinv, ssrc)
    k_bucket<<<NB, 256, 0, stream>>>(part, bucketStart, NB, shift, ssrc, rowptr, dinv, N);

    // layer 1: Bh = fp16( relu(agg(dinv[s]*A[s])*dd + b1) * dd )
    k_agg<1><<<AB, 256, 0, stream>>>(rowptr, ssrc, dinv, Ah, b1, Bh, N);
    // layer 2 shared aggregation: r(=Ah) = fp16( agg(B2)*dd )
    k_agg<2><<<AB, 256, 0, stream>>>(rowptr, ssrc, dinv, Bh, b1, Ah, N);

    k_final2<<<GB, 256, 0, stream>>>(Ah, Wmu, bmu, Wlg, blg, out, N);
}

// Round 11
// 284.551 us; speedup vs baseline: 10.6968x; 1.0396x over previous
//
#include <hip/hip_runtime.h>
#include <hip/hip_fp16.h>

// ---------------------------------------------------------------------------
// GCN encoder: mu, log = GCNConv(relu(GCNConv(x,W1,b1)), W_mu/W_log)
// Identity: segment_sum((h@W)[src]*norm) == segment_sum(h[src]*norm) @ W
// R1: CSR + gather (killed f32-atomic write-through).
// R2-R5: one atomic pass; reg-blocked GEMMs; sharding/ILP on atomics FALSIFIED
//        => device atomics are a hard ~18 Gop/s memory-side limit.
// R7: ZERO global atomics — two-level LDS counting sort builds the CSR.
// R9: fp16 feature buffers: gather payload 256B -> 128B/edge (agg bytes-bound).
// R10: (a) LDS-staged x in the fused GEMM — kills the 16x-redundant broadcast
//      VMEM stream (k_fused1 was L1-issue bound: VALU 27%, FETCH 32MB);
//      (b) part[] packed to u32 (src<<shift | dst&mask) — halves the
//      partial-line scatter traffic in k_part/k_bucket.
// ---------------------------------------------------------------------------

#define EPB 8192   // edges per histogram/partition block

__device__ inline uint2 f4_to_h4(float4 v) {
    __half2 lo = __floats2half2_rn(v.x, v.y);
    __half2 hi = __floats2half2_rn(v.z, v.w);
    uint2 u;
    u.x = *reinterpret_cast<unsigned int*>(&lo);
    u.y = *reinterpret_cast<unsigned int*>(&hi);
    return u;
}
__device__ inline float4 h4_to_f4(uint2 u) {
    __half2 lo = *reinterpret_cast<__half2*>(&u.x);
    __half2 hi = *reinterpret_cast<__half2*>(&u.y);
    float2 a = __half22float2(lo);
    float2 b = __half22float2(hi);
    return make_float4(a.x, a.y, b.x, b.y);
}

// ---- K1: edge blocks -> LDS bucket histogram; gemm blocks -> A = x@W1 (fp16)
__global__ __launch_bounds__(256) void k_fused1(const int* __restrict__ ei, int E,
                                                int* __restrict__ hist, int NB, int shift,
                                                const float* __restrict__ x,
                                                const float* __restrict__ W1,
                                                __half* __restrict__ A, int N, int NEB) {
    __shared__ float Ws[8192];   // 32KB: gemm W-tile; aliased as int hist[<=2048]
    __shared__ float xs[128 * 16];   // 8KB: staged x k-chunk
    int t = threadIdx.x;
    int b = blockIdx.x;
    if (b < NEB) {                       // ---- histogram part ----
        int* h = (int*)Ws;
        for (int k = t; k < NB; k += 256) h[k] = 0;
        __syncthreads();
        int e0 = b * EPB, e1 = min(e0 + EPB, E);
        for (int e = e0 + t * 4; e < e1; e += 1024) {
            if (e + 3 < e1 && ((E & 3) == 0)) {
                int4 d4 = *reinterpret_cast<const int4*>(ei + E + e);
                atomicAdd(&h[d4.x >> shift], 1);
                atomicAdd(&h[d4.y >> shift], 1);
                atomicAdd(&h[d4.z >> shift], 1);
                atomicAdd(&h[d4.w >> shift], 1);
            } else {
                for (int k2 = 0; k2 < 4; ++k2) {
                    int e2 = e + k2;
                    if (e2 < e1) atomicAdd(&h[ei[E + e2] >> shift], 1);
                }
            }
        }
        __syncthreads();
        for (int k = t; k < NB; k += 256) hist[(size_t)b * NB + k] = h[k];
        return;
    }
    // ---- gemm part: 128 rows/block, 8x4/thread, x LDS-staged per 16-k chunk
    int bb = b - NEB;
    for (int i = t; i < 2048; i += 256)
        reinterpret_cast<float4*>(Ws)[i] = reinterpret_cast<const float4*>(W1)[i];
    int cg = t & 15, rg = t >> 4;
    int rowB = bb * 128;
    int row0 = rowB + rg * 8;
    int c4 = cg * 4;
    float4 acc[8];
#pragma unroll
    for (int i = 0; i < 8; ++i) acc[i] = {0.f, 0.f, 0.f, 0.f};
    for (int kc = 0; kc < 128; kc += 16) {
        __syncthreads();                 // xs readers of previous chunk done
        // stage xs[128][16]: 512 float4 slots, 2 per thread, coalesced
#pragma unroll
        for (int q = 0; q < 2; ++q) {
            int slot = q * 256 + t;      // 0..511
            int row = slot >> 2;
            int f4 = (slot & 3) << 2;
            int rr = rowB + row;
            float4 v = {0.f, 0.f, 0.f, 0.f};
            if (rr < N)
                v = *reinterpret_cast<const float4*>(x + (size_t)rr * 128 + kc + f4);
            *reinterpret_cast<float4*>(xs + row * 16 + f4) = v;
        }
        __syncthreads();
#pragma unroll
        for (int kk0 = 0; kk0 < 16; kk0 += 4) {
            float4 xr[8];
#pragma unroll
            for (int i = 0; i < 8; ++i)
                xr[i] = *reinterpret_cast<const float4*>(xs + (rg * 8 + i) * 16 + kk0);
#pragma unroll
            for (int kk = 0; kk < 4; ++kk) {
                float4 w = *reinterpret_cast<const float4*>(Ws + (kc + kk0 + kk) * 64 + c4);
#pragma unroll
                for (int i = 0; i < 8; ++i) {
                    float xv = (&xr[i].x)[kk];
                    acc[i].x = fmaf(xv, w.x, acc[i].x);
                    acc[i].y = fmaf(xv, w.y, acc[i].y);
                    acc[i].z = fmaf(xv, w.z, acc[i].z);
                    acc[i].w = fmaf(xv, w.w, acc[i].w);
                }
            }
        }
    }
#pragma unroll
    for (int i = 0; i < 8; ++i) {
        int rr = row0 + i;
        if (rr < N)
            *reinterpret_cast<uint2*>(A + (size_t)rr * 64 + c4) = f4_to_h4(acc[i]);
    }
}

// ---- K2: in-place column-exclusive prefix over blocks; colTotal out --------
__global__ void k_colpre(int* __restrict__ hist, int* __restrict__ colTotal,
                         int NB, int NBLK) {
    int k = blockIdx.x * 256 + threadIdx.x;
    if (k >= NB) return;
    int run = 0;
#pragma unroll 4
    for (int b = 0; b < NBLK; ++b) {
        int* p = hist + (size_t)b * NB + k;
        int v = *p;
        *p = run;
        run += v;
    }
    colTotal[k] = run;
}

// ---- K3: exclusive scan of colTotal[NB<=2048] -> bucketStart[NB+1] ---------
__global__ __launch_bounds__(256) void k_bscan(const int* __restrict__ colTotal,
                                               int* __restrict__ bucketStart,
                                               int NB, int E,
                                               int* __restrict__ rowptr, int N) {
    __shared__ int sdata[256];
    int t = threadIdx.x;
    int v[8];
    int sum = 0;
#pragma unroll
    for (int i = 0; i < 8; ++i) {
        int k = t * 8 + i;
        v[i] = (k < NB) ? colTotal[k] : 0;
        sum += v[i];
    }
    sdata[t] = sum;
    __syncthreads();
    for (int off = 1; off < 256; off <<= 1) {
        int val = (t >= off) ? sdata[t - off] : 0;
        __syncthreads();
        sdata[t] += val;
        __syncthreads();
    }
    int excl = (t > 0) ? sdata[t - 1] : 0;
#pragma unroll
    for (int i = 0; i < 8; ++i) {
        int k = t * 8 + i;
        if (k < NB) bucketStart[k] = excl;
        excl += v[i];
    }
    if (t == 0) { bucketStart[NB] = E; rowptr[N] = E; }
}

// ---- K4: LDS-cursor partition; entry packed (src<<shift | dst&mask) --------
__global__ __launch_bounds__(256) void k_part(const int* __restrict__ ei, int E,
                                              const int* __restrict__ hist,
                                              const int* __restrict__ bucketStart,
                                              int NB, int shift,
                                              unsigned int* __restrict__ part) {
    __shared__ int cur[2048];
    int t = threadIdx.x, b = blockIdx.x;
    unsigned int mask = (1u << shift) - 1u;
    for (int k = t; k < NB; k += 256)
        cur[k] = hist[(size_t)b * NB + k] + bucketStart[k];
    __syncthreads();
    int e0 = b * EPB, e1 = min(e0 + EPB, E);
    for (int e = e0 + t * 4; e < e1; e += 1024) {
        if (e + 3 < e1 && ((E & 3) == 0)) {
            int4 s4 = *reinterpret_cast<const int4*>(ei + e);
            int4 d4 = *reinterpret_cast<const int4*>(ei + E + e);
            int p;
            p = atomicAdd(&cur[d4.x >> shift], 1);
            part[p] = ((unsigned int)s4.x << shift) | ((unsigned int)d4.x & mask);
            p = atomicAdd(&cur[d4.y >> shift], 1);
            part[p] = ((unsigned int)s4.y << shift) | ((unsigned int)d4.y & mask);
            p = atomicAdd(&cur[d4.z >> shift], 1);
            part[p] = ((unsigned int)s4.z << shift) | ((unsigned int)d4.z & mask);
            p = atomicAdd(&cur[d4.w >> shift], 1);
            part[p] = ((unsigned int)s4.w << shift) | ((unsigned int)d4.w & mask);
        } else {
            for (int k2 = 0; k2 < 4; ++k2) {
                int e2 = e + k2;
                if (e2 < e1) {
                    int s = ei[e2], d = ei[E + e2];
                    int p = atomicAdd(&cur[d >> shift], 1);
                    part[p] = ((unsigned int)s << shift) | ((unsigned int)d & mask);
                }
            }
        }
    }
}

// ---- K5: per-bucket CSR finalize: rowptr, dinv, ssrc -----------------------
__global__ __launch_bounds__(256) void k_bucket(const unsigned int* __restrict__ part,
                                                const int* __restrict__ bucketStart,
                                                int NB, int shift,
                                                int* __restrict__ ssrc,
                                                int* __restrict__ rowptr,
                                                float* __restrict__ dinv, int N) {
    __shared__ int cnt[2048];
    __shared__ int base[2048];
    int t = threadIdx.x, b = blockIdx.x;
    unsigned int mask = (1u << shift) - 1u;
    int lo = bucketStart[b], hi = bucketStart[b + 1];
    int n0 = b << shift;
    int nn = min(1 << shift, N - n0);
    for (int i = t; i < nn; i += 256) cnt[i] = 0;
    __syncthreads();
    for (int e = lo + t; e < hi; e += 256) {
        unsigned int pv = part[e];
        atomicAdd(&cnt[pv & mask], 1);
    }
    __syncthreads();
    if (t == 0) {
        int run = 0;
        for (int i = 0; i < nn; ++i) { base[i] = run; run += cnt[i]; }
    }
    __syncthreads();
    for (int i = t; i < nn; i += 256) {
        rowptr[n0 + i] = lo + base[i];
        dinv[n0 + i] = rsqrtf((float)(cnt[i] + 1));
    }
    __syncthreads();
    for (int e = lo + t; e < hi; e += 256) {
        unsigned int pv = part[e];
        int p = atomicAdd(&base[pv & mask], 1);
        ssrc[lo + p] = (int)(pv >> shift);
    }
}

// ---- CSR gather-aggregate over fp16 rows (128B/edge), unrolled x4 ----------
// EPI==1: feat = A(h);  inner applies dinv[s]; out = fp16( relu((acc)*dd+b1)*dd )
// EPI==2: feat = B2(h); inner pure add;        out = fp16( (acc)*dd )   (= r)
template <int EPI>
__global__ __launch_bounds__(256) void k_agg(const int* __restrict__ rowptr,
                                             const int* __restrict__ ssrc,
                                             const float* __restrict__ dinv,
                                             const __half* __restrict__ feat,
                                             const float* __restrict__ bias,
                                             __half* __restrict__ out, int N) {
    int idx = blockIdx.x * 256 + threadIdx.x;
    int g = idx >> 4;
    if (g >= N) return;
    int fo = idx & 15;                           // uint2 (4-half) offset in row
    const uint2* F = reinterpret_cast<const uint2*>(feat);
    int beg = rowptr[g], end = rowptr[g + 1];
    float dd = dinv[g];
    float4 self = h4_to_f4(F[(size_t)g * 16 + fo]);
    float4 a0, a1 = {0,0,0,0}, a2 = {0,0,0,0}, a3 = {0,0,0,0};
    if (EPI == 1) { a0.x = self.x * dd; a0.y = self.y * dd; a0.z = self.z * dd; a0.w = self.w * dd; }
    else a0 = self;
    int j = beg;
    for (; j + 4 <= end; j += 4) {
        int s0 = ssrc[j], s1 = ssrc[j + 1], s2 = ssrc[j + 2], s3 = ssrc[j + 3];
        float4 v0 = h4_to_f4(F[(size_t)s0 * 16 + fo]);
        float4 v1 = h4_to_f4(F[(size_t)s1 * 16 + fo]);
        float4 v2 = h4_to_f4(F[(size_t)s2 * 16 + fo]);
        float4 v3 = h4_to_f4(F[(size_t)s3 * 16 + fo]);
        if (EPI == 1) {
            float n0 = dinv[s0], n1 = dinv[s1], n2 = dinv[s2], n3 = dinv[s3];
            a0.x = fmaf(v0.x, n0, a0.x); a0.y = fmaf(v0.y, n0, a0.y);
            a0.z = fmaf(v0.z, n0, a0.z); a0.w = fmaf(v0.w, n0, a0.w);
            a1.x = fmaf(v1.x, n1, a1.x); a1.y = fmaf(v1.y, n1, a1.y);
            a1.z = fmaf(v1.z, n1, a1.z); a1.w = fmaf(v1.w, n1, a1.w);
            a2.x = fmaf(v2.x, n2, a2.x); a2.y = fmaf(v2.y, n2, a2.y);
            a2.z = fmaf(v2.z, n2, a2.z); a2.w = fmaf(v2.w, n2, a2.w);
            a3.x = fmaf(v3.x, n3, a3.x); a3.y = fmaf(v3.y, n3, a3.y);
            a3.z = fmaf(v3.z, n3, a3.z); a3.w = fmaf(v3.w, n3, a3.w);
        } else {
            a0.x += v0.x; a0.y += v0.y; a0.z += v0.z; a0.w += v0.w;
            a1.x += v1.x; a1.y += v1.y; a1.z += v1.z; a1.w += v1.w;
            a2.x += v2.x; a2.y += v2.y; a2.z += v2.z; a2.w += v2.w;
            a3.x += v3.x; a3.y += v3.y; a3.z += v3.z; a3.w += v3.w;
        }
    }
    for (; j < end; ++j) {
        int s = ssrc[j];
        float4 v = h4_to_f4(F[(size_t)s * 16 + fo]);
        if (EPI == 1) {
            float ns = dinv[s];
            a1.x = fmaf(v.x, ns, a1.x); a1.y = fmaf(v.y, ns, a1.y);
            a1.z = fmaf(v.z, ns, a1.z); a1.w = fmaf(v.w, ns, a1.w);
        } else {
            a1.x += v.x; a1.y += v.y; a1.z += v.z; a1.w += v.w;
        }
    }
    float4 acc;
    acc.x = (a0.x + a1.x) + (a2.x + a3.x);
    acc.y = (a0.y + a1.y) + (a2.y + a3.y);
    acc.z = (a0.z + a1.z) + (a2.z + a3.z);
    acc.w = (a0.w + a1.w) + (a2.w + a3.w);
    float4 r;
    if (EPI == 1) {
        const float4 bv = *reinterpret_cast<const float4*>(bias + (fo << 2));
        r.x = fmaf(acc.x, dd, bv.x);
        r.y = fmaf(acc.y, dd, bv.y);
        r.z = fmaf(acc.z, dd, bv.z);
        r.w = fmaf(acc.w, dd, bv.w);
        r.x = r.x > 0.f ? r.x * dd : 0.f;
        r.y = r.y > 0.f ? r.y * dd : 0.f;
        r.z = r.z > 0.f ? r.z * dd : 0.f;
        r.w = r.w > 0.f ? r.w * dd : 0.f;
    } else {
        r.x = acc.x * dd; r.y = acc.y * dd; r.z = acc.z * dd; r.w = acc.w * dd;
    }
    reinterpret_cast<uint2*>(out)[(size_t)g * 16 + fo] = f4_to_h4(r);
}

// ---- Final dual GEMV (fp16 R): 128 rows/block, 8x4/thread ------------------
__global__ __launch_bounds__(256) void k_final2(const __half* __restrict__ R,
                                                const float* __restrict__ Wmu,
                                                const float* __restrict__ bmu,
                                                const float* __restrict__ Wlg,
                                                const float* __restrict__ blg,
                                                float* __restrict__ out, int N) {
    __shared__ float Ws[64 * 64];
    int t = threadIdx.x;
    for (int i = t; i < 4096; i += 256) {
        int k = i >> 6, c = i & 63;
        Ws[i] = (c < 32) ? Wmu[(k << 5) + c] : Wlg[(k << 5) + (c - 32)];
    }
    __syncthreads();
    int cg = t & 15, rg = t >> 4;
    int row0 = blockIdx.x * 128 + rg * 8;
    int c4 = cg * 4;
    float4 bv;
    if (c4 < 32) bv = *reinterpret_cast<const float4*>(bmu + c4);
    else         bv = *reinterpret_cast<const float4*>(blg + c4 - 32);
    float4 acc[8];
#pragma unroll
    for (int i = 0; i < 8; ++i) acc[i] = bv;
    const uint2* R2 = reinterpret_cast<const uint2*>(R);
    for (int k0 = 0; k0 < 64; k0 += 4) {
        float4 xr[8];
#pragma unroll
        for (int i = 0; i < 8; ++i) {
            int rr = row0 + i;
            if (rr >= N) rr = N - 1;
            xr[i] = h4_to_f4(R2[(size_t)rr * 16 + (k0 >> 2)]);
        }
#pragma unroll
        for (int kk = 0; kk < 4; ++kk) {
            float4 w = *reinterpret_cast<const float4*>(Ws + (k0 + kk) * 64 + c4);
#pragma unroll
            for (int i = 0; i < 8; ++i) {
                float xv = (&xr[i].x)[kk];
                acc[i].x = fmaf(xv, w.x, acc[i].x);
                acc[i].y = fmaf(xv, w.y, acc[i].y);
                acc[i].z = fmaf(xv, w.z, acc[i].z);
                acc[i].w = fmaf(xv, w.w, acc[i].w);
            }
        }
    }
#pragma unroll
    for (int i = 0; i < 8; ++i) {
        int rr = row0 + i;
        if (rr < N) {
            float* dst = (c4 < 32) ? (out + (size_t)rr * 32 + c4)
                                   : (out + (size_t)N * 32 + (size_t)rr * 32 + (c4 - 32));
            *reinterpret_cast<float4*>(dst) = acc[i];
        }
    }
}

extern "C" void kernel_launch(void* const* d_in, const int* in_sizes, int n_in,
                              void* d_out, int out_size, void* d_ws, size_t ws_size,
                              hipStream_t stream) {
    const float* x   = (const float*)d_in[0];
    const int*   ei  = (const int*)d_in[1];   // [2,E] flat: src then dst
    const float* W1  = (const float*)d_in[2];
    const float* b1  = (const float*)d_in[3];
    const float* Wmu = (const float*)d_in[4];
    const float* bmu = (const float*)d_in[5];
    const float* Wlg = (const float*)d_in[6];
    const float* blg = (const float*)d_in[7];
    float* out = (float*)d_out;

    const int N = in_sizes[0] / 128;
    const int E = in_sizes[1] / 2;

    int shift = 6;
    while ((((N + (1 << shift) - 1) >> shift)) > 2048) ++shift;
    const int NB  = (N + (1 << shift) - 1) >> shift;   // buckets (<=2048)
    const int NEB = (E + EPB - 1) / EPB;               // edge blocks
    const int GB  = (N + 127) / 128;                   // gemm blocks
    const int AB  = (int)(((size_t)N * 16 + 255) / 256);

    // workspace (linear, ~41MB):
    // Ah[N*64]h | Bh[N*64]h | ssrc[E] | rowptr[N+1] | dinv[N] | part[E]u32
    // | hist[NEB*NB] | colTotal[NB] | bucketStart[NB+1]
    // r (fp16, agg<2> out) ALIASES Ah — A is dead after agg<1>.
    __half* Ah        = (__half*)d_ws;
    __half* Bh        = Ah + (size_t)N * 64;
    int*    ssrc      = (int*)(Bh + (size_t)N * 64);
    int*    rowptr    = ssrc + E;
    float*  dinv      = (float*)(rowptr + (N + 1));
    unsigned int* part = (unsigned int*)(dinv + N);
    int*    hist      = (int*)(part + E);
    int*    colTotal  = hist + (size_t)NEB * NB;
    int*    bucketStart = colTotal + NB;

    // K1: per-block LDS bucket histograms || x@W1 GEMM (LDS-staged x, fp16 out)
    k_fused1<<<NEB + GB, 256, 0, stream>>>(ei, E, hist, NB, shift, x, W1, Ah, N, NEB);
    // K2: column-exclusive prefix over blocks (in place) + colTotal
    k_colpre<<<(NB + 255) / 256, 256, 0, stream>>>(hist, colTotal, NB, NEB);
    // K3: bucket-base scan
    k_bscan<<<1, 256, 0, stream>>>(colTotal, bucketStart, NB, E, rowptr, N);
    // K4: partition packed (src,dst) into bucket-major order via LDS cursors
    k_part<<<NEB, 256, 0, stream>>>(ei, E, hist, bucketStart, NB, shift, part);
    // K5: per-bucket CSR finalize (rowptr, dinv, ssrc)
    k_bucket<<<NB, 256, 0, stream>>>(part, bucketStart, NB, shift, ssrc, rowptr, dinv, N);

    // layer 1: Bh = fp16( relu(agg(dinv[s]*A[s])*dd + b1) * dd )
    k_agg<1><<<AB, 256, 0, stream>>>(rowptr, ssrc, dinv, Ah, b1, Bh, N);
    // layer 2 shared aggregation: r(=Ah) = fp16( agg(B2)*dd )
    k_agg<2><<<AB, 256, 0, stream>>>(rowptr, ssrc, dinv, Bh, b1, Ah, N);

    k_final2<<<GB, 256, 0, stream>>>(Ah, Wmu, bmu, Wlg, blg, out, N);
}